// Round 4
// baseline (416.891 us; speedup 1.0000x reference)
//
#include <hip/hip_runtime.h>
#include <cstdint>
#include <cstddef>

#define N_NODES 50000
#define N_EDGES 400000
#define EN_TOT  (N_EDGES + N_NODES)
#define NEG_SLOPE 0.2f
#define LN_EPS 1e-5f

typedef short bf16x8 __attribute__((ext_vector_type(8)));
typedef float f32x4  __attribute__((ext_vector_type(4)));

__device__ __forceinline__ ushort f2bf(float f) {
    union { float f; uint32_t u; } c; c.f = f;
    uint32_t u = c.u + 0x7FFFu + ((c.u >> 16) & 1u);   // RNE
    return (ushort)(u >> 16);
}
__device__ __forceinline__ uint32_t pk2(float a, float b) {
    return (uint32_t)f2bf(a) | ((uint32_t)f2bf(b) << 16);
}
__device__ __forceinline__ float bf_lo(uint32_t u) {
    union { uint32_t u; float f; } c; c.u = u << 16; return c.f;
}
__device__ __forceinline__ float bf_hi(uint32_t u) {
    union { uint32_t u; float f; } c; c.u = u & 0xFFFF0000u; return c.f;
}
__device__ __forceinline__ float bfu(const ushort* p) {
    union { uint32_t u; float f; } c; c.u = ((uint32_t)*p) << 16; return c.f;
}

// ---------------------------------------------------------------------------
// weights -> bf16.  wb: [Wl 65536 | Wr 65536 | W1 32768 | W2 32768 | att 512]
// ---------------------------------------------------------------------------
__global__ __launch_bounds__(256) void cast_weights(
    const float* __restrict__ Wl, const float* __restrict__ Wr,
    const float* __restrict__ W1, const float* __restrict__ W2,
    const float* __restrict__ att, ushort* __restrict__ wb)
{
    int i = blockIdx.x * 256 + threadIdx.x;          // 770*256 == 197120 exact
    const float* src; int off;
    if (i < 65536)       { src = Wl;  off = i; }
    else if (i < 131072) { src = Wr;  off = i - 65536; }
    else if (i < 163840) { src = W1;  off = i - 131072; }
    else if (i < 196608) { src = W2;  off = i - 163840; }
    else                 { src = att; off = i - 196608; }
    wb[i] = f2bf(src[off]);
}

// ---------------------------------------------------------------------------
// xl/xr GEMM. A = x (fp32 -> bf16 while staging). blockIdx.y picks which
// 4 of 8 col-tiles of Wcat=[Wl;Wr] -> xlb or xrb. Transposed MFMA so each
// lane stores 4 consecutive cols (ushort4).
// ---------------------------------------------------------------------------
__global__ __launch_bounds__(256) void gemm_lr(
    const float* __restrict__ x, const ushort* __restrict__ wcat,
    const float* __restrict__ bl, const float* __restrict__ br,
    ushort* __restrict__ xlb, ushort* __restrict__ xrb)
{
    __shared__ ushort As[128 * 128];
    __shared__ ushort Bs[128 * 128];
    const int tid  = threadIdx.x;
    const int rb   = blockIdx.x * 128;
    const int wave = tid >> 6, lane = tid & 63;
    const int wm   = (wave >> 1) * 64, wn = (wave & 1) * 64;
    const int lr   = lane & 15, lq = lane >> 4;

    const float* bias = (blockIdx.y == 0) ? bl : br;
    ushort* outp      = (blockIdx.y == 0) ? xlb : xrb;
    const int cbk0    = blockIdx.y * 4;

    #pragma unroll
    for (int i = 0; i < 8; ++i) {
        int chunk = tid + i * 256;          // 0..2047
        int rr = chunk >> 4, cc = chunk & 15;
        int gr = rb + rr;
        float4 v0 = make_float4(0.f,0.f,0.f,0.f), v1 = v0;
        if (gr < N_NODES) {
            v0 = *(const float4*)(x + (size_t)gr * 128 + cc * 8);
            v1 = *(const float4*)(x + (size_t)gr * 128 + cc * 8 + 4);
        }
        uint4 h = make_uint4(pk2(v0.x,v0.y), pk2(v0.z,v0.w),
                             pk2(v1.x,v1.y), pk2(v1.z,v1.w));
        *(uint4*)(As + rr * 128 + ((cc ^ (rr & 15)) * 8)) = h;
    }

    for (int t = 0; t < 4; ++t) {
        int cbk = cbk0 + t;
        __syncthreads();
        #pragma unroll
        for (int i = 0; i < 8; ++i) {
            int chunk = tid + i * 256;
            int rr = chunk >> 4, cc = chunk & 15;
            uint4 vb = *(const uint4*)(wcat + (size_t)(cbk * 128 + rr) * 128 + cc * 8);
            *(uint4*)(Bs + rr * 128 + ((cc ^ (rr & 15)) * 8)) = vb;
        }
        __syncthreads();

        f32x4 zero = {0.f,0.f,0.f,0.f};
        f32x4 acc[4][4];
        #pragma unroll
        for (int i = 0; i < 4; ++i)
            #pragma unroll
            for (int j = 0; j < 4; ++j) acc[i][j] = zero;

        #pragma unroll
        for (int q = 0; q < 4; ++q) {
            int csw = ((q * 4 + lq) ^ lr) * 8;
            bf16x8 bfr[4], af[4];
            #pragma unroll
            for (int i = 0; i < 4; ++i) {
                bfr[i] = *(const bf16x8*)(Bs + (wm + i * 16 + lr) * 128 + csw);
                af[i]  = *(const bf16x8*)(As + (wn + i * 16 + lr) * 128 + csw);
            }
            #pragma unroll
            for (int i = 0; i < 4; ++i)
                #pragma unroll
                for (int j = 0; j < 4; ++j)
                    acc[i][j] = __builtin_amdgcn_mfma_f32_16x16x32_bf16(
                        bfr[i], af[j], acc[i][j], 0, 0, 0);
        }

        const int cloc = (cbk & 3) * 128;
        #pragma unroll
        for (int i = 0; i < 4; ++i) {
            int wc = wm + i * 16 + lq * 4;
            float4 bv = *(const float4*)(bias + cloc + wc);
            #pragma unroll
            for (int j = 0; j < 4; ++j) {
                int node = rb + wn + j * 16 + lr;
                if (node < N_NODES) {
                    ushort4 o;
                    o.x = f2bf(acc[i][j][0] + bv.x);
                    o.y = f2bf(acc[i][j][1] + bv.y);
                    o.z = f2bf(acc[i][j][2] + bv.z);
                    o.w = f2bf(acc[i][j][3] + bv.w);
                    *(ushort4*)(outp + (size_t)node * 512 + cloc + wc) = o;
                }
            }
        }
    }
}

// ---------------------------------------------------------------------------
// CSR build: count -> single-block scan -> scatter
// ---------------------------------------------------------------------------
__global__ __launch_bounds__(256) void count_deg(const int* __restrict__ dst,
                                                 int* __restrict__ counts)
{
    int i = blockIdx.x * 256 + threadIdx.x;
    if (i >= EN_TOT) return;
    int d = (i < N_EDGES) ? dst[i] : (i - N_EDGES);
    atomicAdd(counts + d, 1);
}

__global__ __launch_bounds__(1024) void scan_all(const int* __restrict__ counts,
                                                 int* __restrict__ offs)
{
    __shared__ int wsum[16];
    __shared__ int wpre[16];
    const int t = threadIdx.x;
    const int lane = t & 63, w = t >> 6;
    const int C = 49;                         // 1024*49 >= 50000
    const int base = t * C;

    int s = 0;
    for (int k = 0; k < C; ++k) {
        int idx = base + k;
        if (idx < N_NODES) s += counts[idx];
    }
    int inc = s;
    #pragma unroll
    for (int d = 1; d < 64; d <<= 1) {
        int v = __shfl_up(inc, d, 64);
        if (lane >= d) inc += v;
    }
    if (lane == 63) wsum[w] = inc;
    __syncthreads();
    if (t < 16) {
        int v = wsum[t];
        int p = v;
        #pragma unroll
        for (int d = 1; d < 16; d <<= 1) {
            int q = __shfl_up(p, d, 64);
            if (t >= d) p += q;
        }
        wpre[t] = p - v;                      // exclusive
    }
    __syncthreads();
    int run = wpre[w] + (inc - s);
    for (int k = 0; k < C; ++k) {
        int idx = base + k;
        if (idx < N_NODES) { offs[idx] = run; run += counts[idx]; }
    }
    if (t == 1023) offs[N_NODES] = wpre[15] + inc;   // grand total == EN_TOT
}

__global__ __launch_bounds__(256) void scatter_edges(
    const int* __restrict__ src, const int* __restrict__ dst,
    const int* __restrict__ offs, int* __restrict__ cursor,
    int* __restrict__ srcList)
{
    int i = blockIdx.x * 256 + threadIdx.x;
    if (i >= EN_TOT) return;
    int s, d;
    if (i < N_EDGES) { s = src[i]; d = dst[i]; }
    else             { s = d = i - N_EDGES; }
    int pos = atomicAdd(cursor + d, 1);
    srcList[offs[d] + pos] = s;
}

// ---------------------------------------------------------------------------
// GATv2 per destination node (one wave each), bf16 gather, 2-edge unrolled
// so the two 4-shuffle reduction chains interleave on the DS pipe.
// + head-mean + bias + residual + LN1 -> x1b (bf16)
// ---------------------------------------------------------------------------
__global__ __launch_bounds__(256) void gat_fused(
    const float* __restrict__ x, const ushort* __restrict__ xl,
    const ushort* __restrict__ xr, const int* __restrict__ offs,
    const int* __restrict__ srcList, const ushort* __restrict__ attb,
    const float* __restrict__ bias, const float* __restrict__ g1,
    const float* __restrict__ be1, ushort* __restrict__ x1b)
{
    const int wave = threadIdx.x >> 6;
    const int lane = threadIdx.x & 63;
    const int v = blockIdx.x * 4 + wave;
    if (v >= N_NODES) return;

    uint4 rw = *(const uint4*)(xr + (size_t)v * 512 + lane * 8);
    uint4 aw = *(const uint4*)(attb + lane * 8);
    float r[8], at[8];
    r[0]=bf_lo(rw.x); r[1]=bf_hi(rw.x); r[2]=bf_lo(rw.y); r[3]=bf_hi(rw.y);
    r[4]=bf_lo(rw.z); r[5]=bf_hi(rw.z); r[6]=bf_lo(rw.w); r[7]=bf_hi(rw.w);
    at[0]=bf_lo(aw.x); at[1]=bf_hi(aw.x); at[2]=bf_lo(aw.y); at[3]=bf_hi(aw.y);
    at[4]=bf_lo(aw.z); at[5]=bf_hi(aw.z); at[6]=bf_lo(aw.w); at[7]=bf_hi(aw.w);

    float acc[8] = {0.f,0.f,0.f,0.f,0.f,0.f,0.f,0.f};
    float lh = 0.f;

    const int jb = offs[v], je = offs[v + 1];
    int j = jb;
    while (j + 1 < je) {
        int u0 = srcList[j], u1 = srcList[j + 1];
        uint4 c0 = *(const uint4*)(xl + (size_t)u0 * 512 + lane * 8);
        uint4 c1 = *(const uint4*)(xl + (size_t)u1 * 512 + lane * 8);
        float b0[8], b1[8];
        b0[0]=bf_lo(c0.x); b0[1]=bf_hi(c0.x); b0[2]=bf_lo(c0.y); b0[3]=bf_hi(c0.y);
        b0[4]=bf_lo(c0.z); b0[5]=bf_hi(c0.z); b0[6]=bf_lo(c0.w); b0[7]=bf_hi(c0.w);
        b1[0]=bf_lo(c1.x); b1[1]=bf_hi(c1.x); b1[2]=bf_lo(c1.y); b1[3]=bf_hi(c1.y);
        b1[4]=bf_lo(c1.z); b1[5]=bf_hi(c1.z); b1[6]=bf_lo(c1.w); b1[7]=bf_hi(c1.w);
        float p0 = 0.f, p1 = 0.f;
        #pragma unroll
        for (int k = 0; k < 8; ++k) {
            float s0 = b0[k] + r[k];
            float s1 = b1[k] + r[k];
            float l0 = fmaxf(s0, 0.f) + NEG_SLOPE * fminf(s0, 0.f);
            float l1 = fmaxf(s1, 0.f) + NEG_SLOPE * fminf(s1, 0.f);
            p0 = fmaf(l0, at[k], p0);
            p1 = fmaf(l1, at[k], p1);
        }
        p0 += __shfl_xor(p0, 1, 64);  p1 += __shfl_xor(p1, 1, 64);
        p0 += __shfl_xor(p0, 2, 64);  p1 += __shfl_xor(p1, 2, 64);
        p0 += __shfl_xor(p0, 4, 64);  p1 += __shfl_xor(p1, 4, 64);
        p0 += __shfl_xor(p0, 8, 64);  p1 += __shfl_xor(p1, 8, 64);
        float w0 = __expf(p0), w1 = __expf(p1);
        lh += w0 + w1;
        #pragma unroll
        for (int k = 0; k < 8; ++k)
            acc[k] = fmaf(w0, b0[k], fmaf(w1, b1[k], acc[k]));
        j += 2;
    }
    if (j < je) {
        int u0 = srcList[j];
        uint4 c0 = *(const uint4*)(xl + (size_t)u0 * 512 + lane * 8);
        float b0[8];
        b0[0]=bf_lo(c0.x); b0[1]=bf_hi(c0.x); b0[2]=bf_lo(c0.y); b0[3]=bf_hi(c0.y);
        b0[4]=bf_lo(c0.z); b0[5]=bf_hi(c0.z); b0[6]=bf_lo(c0.w); b0[7]=bf_hi(c0.w);
        float p0 = 0.f;
        #pragma unroll
        for (int k = 0; k < 8; ++k) {
            float s0 = b0[k] + r[k];
            float l0 = fmaxf(s0, 0.f) + NEG_SLOPE * fminf(s0, 0.f);
            p0 = fmaf(l0, at[k], p0);
        }
        p0 += __shfl_xor(p0, 1, 64);
        p0 += __shfl_xor(p0, 2, 64);
        p0 += __shfl_xor(p0, 4, 64);
        p0 += __shfl_xor(p0, 8, 64);
        float w0 = __expf(p0);
        lh += w0;
        #pragma unroll
        for (int k = 0; k < 8; ++k) acc[k] = fmaf(w0, b0[k], acc[k]);
    }

    const float inv = 1.0f / lh;
    const int d0 = (lane & 15) * 8;
    const size_t xo = (size_t)v * 128 + d0;

    float4 xv0 = *(const float4*)(x + xo);
    float4 xv1 = *(const float4*)(x + xo + 4);
    float4 bb0 = *(const float4*)(bias + d0);
    float4 bb1 = *(const float4*)(bias + d0 + 4);
    float xr8[8] = {xv0.x,xv0.y,xv0.z,xv0.w,xv1.x,xv1.y,xv1.z,xv1.w};
    float bi8[8] = {bb0.x,bb0.y,bb0.z,bb0.w,bb1.x,bb1.y,bb1.z,bb1.w};

    float y[8];
    float s = 0.f;
    #pragma unroll
    for (int k = 0; k < 8; ++k) {
        float o = acc[k] * inv;
        o += __shfl_xor(o, 16, 64);
        o += __shfl_xor(o, 32, 64);
        float yy = xr8[k] + o * 0.25f + bi8[k];
        y[k] = yy;
        s += yy;
    }
    s += __shfl_xor(s, 1, 64);
    s += __shfl_xor(s, 2, 64);
    s += __shfl_xor(s, 4, 64);
    s += __shfl_xor(s, 8, 64);
    float mu = s * (1.0f / 128.0f);
    float ss = 0.f;
    #pragma unroll
    for (int k = 0; k < 8; ++k) { float d = y[k] - mu; ss += d * d; }
    ss += __shfl_xor(ss, 1, 64);
    ss += __shfl_xor(ss, 2, 64);
    ss += __shfl_xor(ss, 4, 64);
    ss += __shfl_xor(ss, 8, 64);
    float rs = rsqrtf(ss * (1.0f / 128.0f) + LN_EPS);

    if ((lane >> 4) == 0) {                   // quarters hold identical y
        float4 g0 = *(const float4*)(g1 + d0);
        float4 g4 = *(const float4*)(g1 + d0 + 4);
        float4 e0 = *(const float4*)(be1 + d0);
        float4 e4 = *(const float4*)(be1 + d0 + 4);
        float gg[8] = {g0.x,g0.y,g0.z,g0.w,g4.x,g4.y,g4.z,g4.w};
        float ee[8] = {e0.x,e0.y,e0.z,e0.w,e4.x,e4.y,e4.z,e4.w};
        float z[8];
        #pragma unroll
        for (int k = 0; k < 8; ++k) z[k] = (y[k] - mu) * rs * gg[k] + ee[k];
        ushort4 zb0, zb1;
        zb0.x=f2bf(z[0]); zb0.y=f2bf(z[1]); zb0.z=f2bf(z[2]); zb0.w=f2bf(z[3]);
        zb1.x=f2bf(z[4]); zb1.y=f2bf(z[5]); zb1.z=f2bf(z[6]); zb1.w=f2bf(z[7]);
        *(ushort4*)(x1b + xo)     = zb0;
        *(ushort4*)(x1b + xo + 4) = zb1;
    }
}

// ---------------------------------------------------------------------------
// Fused FFN: h = GELU(x1b@W1^T+b1); f = h@W2^T+b2; out = LN2(x1b + f).
// Hidden tile lives in LDS (Ts). Per block: 128 nodes, self-contained.
// ---------------------------------------------------------------------------
__global__ __launch_bounds__(256) void ffn_fused(
    const ushort* __restrict__ x1b, const ushort* __restrict__ w1b,
    const float* __restrict__ b1, const ushort* __restrict__ w2b,
    const float* __restrict__ b2, const float* __restrict__ g2,
    const float* __restrict__ be2, float* __restrict__ out)
{
    __shared__ ushort As[128 * 128];   // x1b tile       32 KB
    __shared__ ushort Bs[128 * 128];   // weight tile    32 KB
    __shared__ ushort Ts[128 * 128];   // hidden half    32 KB
    const int tid  = threadIdx.x;
    const int rb   = blockIdx.x * 128;
    const int wave = tid >> 6, lane = tid & 63;
    const int wm   = (wave >> 1) * 64, wn = (wave & 1) * 64;
    const int lr   = lane & 15, lq = lane >> 4;

    #pragma unroll
    for (int i = 0; i < 8; ++i) {
        int chunk = tid + i * 256;
        int rr = chunk >> 4, cc = chunk & 15;
        int gr = rb + rr;
        uint4 va = make_uint4(0u,0u,0u,0u);
        if (gr < N_NODES) va = *(const uint4*)(x1b + (size_t)gr * 128 + cc * 8);
        *(uint4*)(As + rr * 128 + ((cc ^ (rr & 15)) * 8)) = va;
    }

    f32x4 zero = {0.f,0.f,0.f,0.f};
    f32x4 acc2[4][4];
    #pragma unroll
    for (int i = 0; i < 4; ++i)
        #pragma unroll
        for (int j = 0; j < 4; ++j) acc2[i][j] = zero;

    for (int half = 0; half < 2; ++half) {
        __syncthreads();
        // stage W1 half
        #pragma unroll
        for (int i = 0; i < 8; ++i) {
            int chunk = tid + i * 256;
            int rr = chunk >> 4, cc = chunk & 15;
            uint4 vb = *(const uint4*)(w1b + (size_t)(half * 128 + rr) * 128 + cc * 8);
            *(uint4*)(Bs + rr * 128 + ((cc ^ (rr & 15)) * 8)) = vb;
        }
        __syncthreads();

        f32x4 acc1[4][4];
        #pragma unroll
        for (int i = 0; i < 4; ++i)
            #pragma unroll
            for (int j = 0; j < 4; ++j) acc1[i][j] = zero;

        #pragma unroll
        for (int q = 0; q < 4; ++q) {
            int csw = ((q * 4 + lq) ^ lr) * 8;
            bf16x8 bfr[4], af[4];
            #pragma unroll
            for (int i = 0; i < 4; ++i) {
                bfr[i] = *(const bf16x8*)(Bs + (wm + i * 16 + lr) * 128 + csw);
                af[i]  = *(const bf16x8*)(As + (wn + i * 16 + lr) * 128 + csw);
            }
            #pragma unroll
            for (int i = 0; i < 4; ++i)
                #pragma unroll
                for (int j = 0; j < 4; ++j)
                    acc1[i][j] = __builtin_amdgcn_mfma_f32_16x16x32_bf16(
                        bfr[i], af[j], acc1[i][j], 0, 0, 0);
        }

        // GELU + write hidden to Ts (node-major, swizzled)
        #pragma unroll
        for (int i = 0; i < 4; ++i) {
            int wc = wm + i * 16 + lq * 4;
            float4 bv = *(const float4*)(b1 + half * 128 + wc);
            #pragma unroll
            for (int j = 0; j < 4; ++j) {
                int nl = wn + j * 16 + lr;
                float v0 = acc1[i][j][0] + bv.x;
                float v1 = acc1[i][j][1] + bv.y;
                float v2 = acc1[i][j][2] + bv.z;
                float v3 = acc1[i][j][3] + bv.w;
                v0 = v0 * 0.5f * (1.0f + erff(v0 * 0.70710678118654752f));
                v1 = v1 * 0.5f * (1.0f + erff(v1 * 0.70710678118654752f));
                v2 = v2 * 0.5f * (1.0f + erff(v2 * 0.70710678118654752f));
                v3 = v3 * 0.5f * (1.0f + erff(v3 * 0.70710678118654752f));
                ushort4 o;
                o.x = f2bf(v0); o.y = f2bf(v1); o.z = f2bf(v2); o.w = f2bf(v3);
                int sw = (((wc >> 3) ^ (nl & 15)) * 8) + (wc & 7);
                *(ushort4*)(Ts + nl * 128 + sw) = o;
            }
        }
        __syncthreads();
        // stage W2 K-slice
        #pragma unroll
        for (int i = 0; i < 8; ++i) {
            int chunk = tid + i * 256;
            int rr = chunk >> 4, cc = chunk & 15;
            uint4 vb = *(const uint4*)(w2b + (size_t)rr * 256 + half * 128 + cc * 8);
            *(uint4*)(Bs + rr * 128 + ((cc ^ (rr & 15)) * 8)) = vb;
        }
        __syncthreads();

        #pragma unroll
        for (int q = 0; q < 4; ++q) {
            int csw = ((q * 4 + lq) ^ lr) * 8;
            bf16x8 bfr[4], af[4];
            #pragma unroll
            for (int i = 0; i < 4; ++i) {
                bfr[i] = *(const bf16x8*)(Bs + (wm + i * 16 + lr) * 128 + csw);
                af[i]  = *(const bf16x8*)(Ts + (wn + i * 16 + lr) * 128 + csw);
            }
            #pragma unroll
            for (int i = 0; i < 4; ++i)
                #pragma unroll
                for (int j = 0; j < 4; ++j)
                    acc2[i][j] = __builtin_amdgcn_mfma_f32_16x16x32_bf16(
                        bfr[i], af[j], acc2[i][j], 0, 0, 0);
        }
    }

    __syncthreads();                          // As reusable for stats
    float* sums = (float*)As;                 // [2][128]
    float* ssqs = (float*)(As + 2048);        // [2][128]

    #pragma unroll
    for (int j = 0; j < 4; ++j) {
        int node = rb + wn + j * 16 + lr;
        float s = 0.f, q2 = 0.f;
        #pragma unroll
        for (int i = 0; i < 4; ++i) {
            int wc = wm + i * 16 + lq * 4;
            float4 bv = *(const float4*)(b2 + wc);
            float x0 = 0.f, x1r = 0.f, x2 = 0.f, x3 = 0.f;
            if (node < N_NODES) {
                ushort4 xv = *(const ushort4*)(x1b + (size_t)node * 128 + wc);
                x0 = bfu(&xv.x); x1r = bfu(&xv.y); x2 = bfu(&xv.z); x3 = bfu(&xv.w);
            }
            float y0 = acc2[i][j][0] + bv.x + x0;
            float y1 = acc2[i][j][1] + bv.y + x1r;
            float y2 = acc2[i][j][2] + bv.z + x2;
            float y3 = acc2[i][j][3] + bv.w + x3;
            acc2[i][j][0] = y0; acc2[i][j][1] = y1;
            acc2[i][j][2] = y2; acc2[i][j][3] = y3;
            s  += y0 + y1 + y2 + y3;
            q2 += y0*y0 + y1*y1 + y2*y2 + y3*y3;
        }
        s  += __shfl_xor(s, 16, 64);  s  += __shfl_xor(s, 32, 64);
        q2 += __shfl_xor(q2, 16, 64); q2 += __shfl_xor(q2, 32, 64);
        if (lq == 0) {
            int half = wm >> 6;
            sums[half * 128 + wn + j * 16 + lr] = s;
            ssqs[half * 128 + wn + j * 16 + lr] = q2;
        }
    }
    __syncthreads();

    #pragma unroll
    for (int j = 0; j < 4; ++j) {
        int nl = wn + j * 16 + lr;
        int node = rb + nl;
        if (node >= N_NODES) continue;
        float tot = sums[nl] + sums[128 + nl];
        float tq  = ssqs[nl] + ssqs[128 + nl];
        float mu  = tot * (1.0f / 128.0f);
        float var = tq * (1.0f / 128.0f) - mu * mu;
        float rs  = rsqrtf(var + LN_EPS);
        #pragma unroll
        for (int i = 0; i < 4; ++i) {
            int wc = wm + i * 16 + lq * 4;
            float4 gv = *(const float4*)(g2 + wc);
            float4 ev = *(const float4*)(be2 + wc);
            float4 o;
            o.x = (acc2[i][j][0] - mu) * rs * gv.x + ev.x;
            o.y = (acc2[i][j][1] - mu) * rs * gv.y + ev.y;
            o.z = (acc2[i][j][2] - mu) * rs * gv.z + ev.z;
            o.w = (acc2[i][j][3] - mu) * rs * gv.w + ev.w;
            *(float4*)(out + (size_t)node * 128 + wc) = o;
        }
    }
}

// ---------------------------------------------------------------------------
extern "C" void kernel_launch(void* const* d_in, const int* in_sizes, int n_in,
                              void* d_out, int out_size, void* d_ws, size_t ws_size,
                              hipStream_t stream)
{
    const float* x    = (const float*)d_in[0];
    const int*   ei   = (const int*)  d_in[1];
    const float* Wl   = (const float*)d_in[2];
    const float* bl   = (const float*)d_in[3];
    const float* Wr   = (const float*)d_in[4];
    const float* br   = (const float*)d_in[5];
    const float* att  = (const float*)d_in[6];
    const float* bias = (const float*)d_in[7];
    const float* g1   = (const float*)d_in[8];
    const float* be1  = (const float*)d_in[9];
    const float* W1   = (const float*)d_in[10];
    const float* b1   = (const float*)d_in[11];
    const float* W2   = (const float*)d_in[12];
    const float* b2   = (const float*)d_in[13];
    const float* g2   = (const float*)d_in[14];
    const float* be2  = (const float*)d_in[15];
    float* out = (float*)d_out;

    char* ws = (char*)d_ws;
    size_t off = 0;
    auto alloc = [&](size_t bytes) -> void* {
        void* p = ws + off;
        off = (off + bytes + 255) & ~(size_t)255;
        return p;
    };
    ushort* xlb  = (ushort*)alloc((size_t)N_NODES * 512 * 2);
    ushort* xrb  = (ushort*)alloc((size_t)N_NODES * 512 * 2);
    ushort* x1b  = (ushort*)alloc((size_t)N_NODES * 128 * 2);
    ushort* wb   = (ushort*)alloc((size_t)197120 * 2);
    int*   offs    = (int*)alloc((size_t)(N_NODES + 1) * 4);
    int*   counts  = (int*)alloc((size_t)N_NODES * 4 * 2);
    int*   cursor  = counts + N_NODES;
    int*   srcList = (int*)alloc((size_t)EN_TOT * 4);

    ushort* wcat = wb;              // [Wl;Wr] 1024x128
    ushort* w1b  = wb + 131072;
    ushort* w2b  = wb + 163840;
    ushort* attb = wb + 196608;

    hipMemsetAsync(counts, 0, (size_t)N_NODES * 8, stream);

    cast_weights<<<770, 256, 0, stream>>>(Wl, Wr, W1, W2, att, wb);

    gemm_lr<<<dim3(391, 2), 256, 0, stream>>>(x, wcat, bl, br, xlb, xrb);

    count_deg<<<(EN_TOT + 255) / 256, 256, 0, stream>>>(ei + N_EDGES, counts);
    scan_all<<<1, 1024, 0, stream>>>(counts, offs);
    scatter_edges<<<(EN_TOT + 255) / 256, 256, 0, stream>>>(ei, ei + N_EDGES,
                                                           offs, cursor, srcList);

    gat_fused<<<12500, 256, 0, stream>>>(x, xlb, xrb, offs, srcList, attb,
                                         bias, g1, be1, x1b);

    ffn_fused<<<391, 256, 0, stream>>>(x1b, w1b, b1, w2b, b2, g2, be2, out);
}

// Round 5
// 335.724 us; speedup vs baseline: 1.2418x; 1.2418x over previous
//
#include <hip/hip_runtime.h>
#include <cstdint>
#include <cstddef>

#define N_NODES 50000
#define N_EDGES 400000
#define EN_TOT  (N_EDGES + N_NODES)
#define NC_SCAN ((N_NODES + 511) / 512)   // 98
#define NEG_SLOPE 0.2f
#define LN_EPS 1e-5f

typedef short bf16x8 __attribute__((ext_vector_type(8)));
typedef float f32x4  __attribute__((ext_vector_type(4)));

__device__ __forceinline__ ushort f2bf(float f) {
    union { float f; uint32_t u; } c; c.f = f;
    uint32_t u = c.u + 0x7FFFu + ((c.u >> 16) & 1u);   // RNE
    return (ushort)(u >> 16);
}
__device__ __forceinline__ uint32_t pk2(float a, float b) {
    return (uint32_t)f2bf(a) | ((uint32_t)f2bf(b) << 16);
}
__device__ __forceinline__ float bf_lo(uint32_t u) {
    union { uint32_t u; float f; } c; c.u = u << 16; return c.f;
}
__device__ __forceinline__ float bf_hi(uint32_t u) {
    union { uint32_t u; float f; } c; c.u = u & 0xFFFF0000u; return c.f;
}
__device__ __forceinline__ float bfu(const ushort* p) {
    union { uint32_t u; float f; } c; c.u = ((uint32_t)*p) << 16; return c.f;
}

// ---------------------------------------------------------------------------
// weights -> bf16.  wb: [Wl 65536 | Wr 65536 | W1 32768 | W2 32768 | att 512]
// ---------------------------------------------------------------------------
__global__ __launch_bounds__(256) void cast_weights(
    const float* __restrict__ Wl, const float* __restrict__ Wr,
    const float* __restrict__ W1, const float* __restrict__ W2,
    const float* __restrict__ att, ushort* __restrict__ wb)
{
    int i = blockIdx.x * 256 + threadIdx.x;          // 770*256 == 197120 exact
    const float* src; int off;
    if (i < 65536)       { src = Wl;  off = i; }
    else if (i < 131072) { src = Wr;  off = i - 65536; }
    else if (i < 163840) { src = W1;  off = i - 131072; }
    else if (i < 196608) { src = W2;  off = i - 163840; }
    else                 { src = att; off = i - 196608; }
    wb[i] = f2bf(src[off]);
}

// ---------------------------------------------------------------------------
// xl/xr GEMM. A = x (fp32 -> bf16 while staging). blockIdx.y picks which
// 4 of 8 col-tiles of Wcat=[Wl;Wr] -> xlb or xrb. Transposed MFMA so each
// lane stores 4 consecutive cols (ushort4).
// ---------------------------------------------------------------------------
__global__ __launch_bounds__(256) void gemm_lr(
    const float* __restrict__ x, const ushort* __restrict__ wcat,
    const float* __restrict__ bl, const float* __restrict__ br,
    ushort* __restrict__ xlb, ushort* __restrict__ xrb)
{
    __shared__ ushort As[128 * 128];
    __shared__ ushort Bs[128 * 128];
    const int tid  = threadIdx.x;
    const int rb   = blockIdx.x * 128;
    const int wave = tid >> 6, lane = tid & 63;
    const int wm   = (wave >> 1) * 64, wn = (wave & 1) * 64;
    const int lr   = lane & 15, lq = lane >> 4;

    const float* bias = (blockIdx.y == 0) ? bl : br;
    ushort* outp      = (blockIdx.y == 0) ? xlb : xrb;
    const int cbk0    = blockIdx.y * 4;

    #pragma unroll
    for (int i = 0; i < 8; ++i) {
        int chunk = tid + i * 256;          // 0..2047
        int rr = chunk >> 4, cc = chunk & 15;
        int gr = rb + rr;
        float4 v0 = make_float4(0.f,0.f,0.f,0.f), v1 = v0;
        if (gr < N_NODES) {
            v0 = *(const float4*)(x + (size_t)gr * 128 + cc * 8);
            v1 = *(const float4*)(x + (size_t)gr * 128 + cc * 8 + 4);
        }
        uint4 h = make_uint4(pk2(v0.x,v0.y), pk2(v0.z,v0.w),
                             pk2(v1.x,v1.y), pk2(v1.z,v1.w));
        *(uint4*)(As + rr * 128 + ((cc ^ (rr & 15)) * 8)) = h;
    }

    for (int t = 0; t < 4; ++t) {
        int cbk = cbk0 + t;
        __syncthreads();
        #pragma unroll
        for (int i = 0; i < 8; ++i) {
            int chunk = tid + i * 256;
            int rr = chunk >> 4, cc = chunk & 15;
            uint4 vb = *(const uint4*)(wcat + (size_t)(cbk * 128 + rr) * 128 + cc * 8);
            *(uint4*)(Bs + rr * 128 + ((cc ^ (rr & 15)) * 8)) = vb;
        }
        __syncthreads();

        f32x4 zero = {0.f,0.f,0.f,0.f};
        f32x4 acc[4][4];
        #pragma unroll
        for (int i = 0; i < 4; ++i)
            #pragma unroll
            for (int j = 0; j < 4; ++j) acc[i][j] = zero;

        #pragma unroll
        for (int q = 0; q < 4; ++q) {
            int csw = ((q * 4 + lq) ^ lr) * 8;
            bf16x8 bfr[4], af[4];
            #pragma unroll
            for (int i = 0; i < 4; ++i) {
                bfr[i] = *(const bf16x8*)(Bs + (wm + i * 16 + lr) * 128 + csw);
                af[i]  = *(const bf16x8*)(As + (wn + i * 16 + lr) * 128 + csw);
            }
            #pragma unroll
            for (int i = 0; i < 4; ++i)
                #pragma unroll
                for (int j = 0; j < 4; ++j)
                    acc[i][j] = __builtin_amdgcn_mfma_f32_16x16x32_bf16(
                        bfr[i], af[j], acc[i][j], 0, 0, 0);
        }

        const int cloc = (cbk & 3) * 128;
        #pragma unroll
        for (int i = 0; i < 4; ++i) {
            int wc = wm + i * 16 + lq * 4;
            float4 bv = *(const float4*)(bias + cloc + wc);
            #pragma unroll
            for (int j = 0; j < 4; ++j) {
                int node = rb + wn + j * 16 + lr;
                if (node < N_NODES) {
                    ushort4 o;
                    o.x = f2bf(acc[i][j][0] + bv.x);
                    o.y = f2bf(acc[i][j][1] + bv.y);
                    o.z = f2bf(acc[i][j][2] + bv.z);
                    o.w = f2bf(acc[i][j][3] + bv.w);
                    *(ushort4*)(outp + (size_t)node * 512 + cloc + wc) = o;
                }
            }
        }
    }
}

// ---------------------------------------------------------------------------
// CSR build: count -> 3-kernel multi-block scan -> scatter  (R3 version)
// ---------------------------------------------------------------------------
__global__ __launch_bounds__(256) void count_deg(const int* __restrict__ dst,
                                                 int* __restrict__ counts)
{
    int i = blockIdx.x * 256 + threadIdx.x;
    if (i >= EN_TOT) return;
    int d = (i < N_EDGES) ? dst[i] : (i - N_EDGES);
    atomicAdd(counts + d, 1);
}

__global__ __launch_bounds__(64) void scan1(const int* __restrict__ counts,
                                            int* __restrict__ csum)
{
    int lane = threadIdx.x;
    int base = blockIdx.x * 512 + lane * 8;
    int s = 0;
    #pragma unroll
    for (int k = 0; k < 8; ++k) {
        int idx = base + k;
        if (idx < N_NODES) s += counts[idx];
    }
    #pragma unroll
    for (int m = 32; m; m >>= 1) s += __shfl_xor(s, m, 64);
    if (lane == 0) csum[blockIdx.x] = s;
}

__global__ __launch_bounds__(64) void scan2(int* __restrict__ csum,
                                            int* __restrict__ offs)
{
    int l = threadIdx.x;
    int v0 = (l < NC_SCAN) ? csum[l] : 0;
    int v1 = (l + 64 < NC_SCAN) ? csum[l + 64] : 0;
    int s0 = v0;
    #pragma unroll
    for (int d = 1; d < 64; d <<= 1) {
        int t = __shfl_up(s0, d, 64);
        if (l >= d) s0 += t;
    }
    int tot0 = __shfl(s0, 63, 64);
    int s1 = v1;
    #pragma unroll
    for (int d = 1; d < 64; d <<= 1) {
        int t = __shfl_up(s1, d, 64);
        if (l >= d) s1 += t;
    }
    int tot1 = __shfl(s1, 63, 64);
    if (l < NC_SCAN) csum[l] = s0 - v0;
    if (l + 64 < NC_SCAN) csum[l + 64] = tot0 + s1 - v1;
    if (l == 0) offs[N_NODES] = tot0 + tot1;
}

__global__ __launch_bounds__(64) void scan3(const int* __restrict__ counts,
                                            const int* __restrict__ csum,
                                            int* __restrict__ offs)
{
    int lane = threadIdx.x;
    int base = blockIdx.x * 512 + lane * 8;
    int cnt[8];
    int s = 0;
    #pragma unroll
    for (int k = 0; k < 8; ++k) {
        int idx = base + k;
        cnt[k] = (idx < N_NODES) ? counts[idx] : 0;
        s += cnt[k];
    }
    int inc = s;
    #pragma unroll
    for (int d = 1; d < 64; d <<= 1) {
        int t = __shfl_up(inc, d, 64);
        if (lane >= d) inc += t;
    }
    int run = csum[blockIdx.x] + (inc - s);
    #pragma unroll
    for (int k = 0; k < 8; ++k) {
        int idx = base + k;
        if (idx < N_NODES) { offs[idx] = run; run += cnt[k]; }
    }
}

__global__ __launch_bounds__(256) void scatter_edges(
    const int* __restrict__ src, const int* __restrict__ dst,
    const int* __restrict__ offs, int* __restrict__ cursor,
    int* __restrict__ srcList)
{
    int i = blockIdx.x * 256 + threadIdx.x;
    if (i >= EN_TOT) return;
    int s, d;
    if (i < N_EDGES) { s = src[i]; d = dst[i]; }
    else             { s = d = i - N_EDGES; }
    int pos = atomicAdd(cursor + d, 1);
    srcList[offs[d] + pos] = s;
}

// ---------------------------------------------------------------------------
// GATv2 per destination node (one wave each), bf16 gather, 2-edge unrolled
// so the two 4-shuffle reduction chains interleave on the DS pipe.
// + head-mean + bias + residual + LN1 -> x1b (bf16)
// ---------------------------------------------------------------------------
__global__ __launch_bounds__(256) void gat_fused(
    const float* __restrict__ x, const ushort* __restrict__ xl,
    const ushort* __restrict__ xr, const int* __restrict__ offs,
    const int* __restrict__ srcList, const ushort* __restrict__ attb,
    const float* __restrict__ bias, const float* __restrict__ g1,
    const float* __restrict__ be1, ushort* __restrict__ x1b)
{
    const int wave = threadIdx.x >> 6;
    const int lane = threadIdx.x & 63;
    const int v = blockIdx.x * 4 + wave;
    if (v >= N_NODES) return;

    uint4 rw = *(const uint4*)(xr + (size_t)v * 512 + lane * 8);
    uint4 aw = *(const uint4*)(attb + lane * 8);
    float r[8], at[8];
    r[0]=bf_lo(rw.x); r[1]=bf_hi(rw.x); r[2]=bf_lo(rw.y); r[3]=bf_hi(rw.y);
    r[4]=bf_lo(rw.z); r[5]=bf_hi(rw.z); r[6]=bf_lo(rw.w); r[7]=bf_hi(rw.w);
    at[0]=bf_lo(aw.x); at[1]=bf_hi(aw.x); at[2]=bf_lo(aw.y); at[3]=bf_hi(aw.y);
    at[4]=bf_lo(aw.z); at[5]=bf_hi(aw.z); at[6]=bf_lo(aw.w); at[7]=bf_hi(aw.w);

    float acc[8] = {0.f,0.f,0.f,0.f,0.f,0.f,0.f,0.f};
    float lh = 0.f;

    const int jb = offs[v], je = offs[v + 1];
    int j = jb;
    while (j + 1 < je) {
        int u0 = srcList[j], u1 = srcList[j + 1];
        uint4 c0 = *(const uint4*)(xl + (size_t)u0 * 512 + lane * 8);
        uint4 c1 = *(const uint4*)(xl + (size_t)u1 * 512 + lane * 8);
        float b0[8], b1[8];
        b0[0]=bf_lo(c0.x); b0[1]=bf_hi(c0.x); b0[2]=bf_lo(c0.y); b0[3]=bf_hi(c0.y);
        b0[4]=bf_lo(c0.z); b0[5]=bf_hi(c0.z); b0[6]=bf_lo(c0.w); b0[7]=bf_hi(c0.w);
        b1[0]=bf_lo(c1.x); b1[1]=bf_hi(c1.x); b1[2]=bf_lo(c1.y); b1[3]=bf_hi(c1.y);
        b1[4]=bf_lo(c1.z); b1[5]=bf_hi(c1.z); b1[6]=bf_lo(c1.w); b1[7]=bf_hi(c1.w);
        float p0 = 0.f, p1 = 0.f;
        #pragma unroll
        for (int k = 0; k < 8; ++k) {
            float s0 = b0[k] + r[k];
            float s1 = b1[k] + r[k];
            float l0 = fmaxf(s0, 0.f) + NEG_SLOPE * fminf(s0, 0.f);
            float l1 = fmaxf(s1, 0.f) + NEG_SLOPE * fminf(s1, 0.f);
            p0 = fmaf(l0, at[k], p0);
            p1 = fmaf(l1, at[k], p1);
        }
        p0 += __shfl_xor(p0, 1, 64);  p1 += __shfl_xor(p1, 1, 64);
        p0 += __shfl_xor(p0, 2, 64);  p1 += __shfl_xor(p1, 2, 64);
        p0 += __shfl_xor(p0, 4, 64);  p1 += __shfl_xor(p1, 4, 64);
        p0 += __shfl_xor(p0, 8, 64);  p1 += __shfl_xor(p1, 8, 64);
        float w0 = __expf(p0), w1 = __expf(p1);
        lh += w0 + w1;
        #pragma unroll
        for (int k = 0; k < 8; ++k)
            acc[k] = fmaf(w0, b0[k], fmaf(w1, b1[k], acc[k]));
        j += 2;
    }
    if (j < je) {
        int u0 = srcList[j];
        uint4 c0 = *(const uint4*)(xl + (size_t)u0 * 512 + lane * 8);
        float b0[8];
        b0[0]=bf_lo(c0.x); b0[1]=bf_hi(c0.x); b0[2]=bf_lo(c0.y); b0[3]=bf_hi(c0.y);
        b0[4]=bf_lo(c0.z); b0[5]=bf_hi(c0.z); b0[6]=bf_lo(c0.w); b0[7]=bf_hi(c0.w);
        float p0 = 0.f;
        #pragma unroll
        for (int k = 0; k < 8; ++k) {
            float s0 = b0[k] + r[k];
            float l0 = fmaxf(s0, 0.f) + NEG_SLOPE * fminf(s0, 0.f);
            p0 = fmaf(l0, at[k], p0);
        }
        p0 += __shfl_xor(p0, 1, 64);
        p0 += __shfl_xor(p0, 2, 64);
        p0 += __shfl_xor(p0, 4, 64);
        p0 += __shfl_xor(p0, 8, 64);
        float w0 = __expf(p0);
        lh += w0;
        #pragma unroll
        for (int k = 0; k < 8; ++k) acc[k] = fmaf(w0, b0[k], acc[k]);
    }

    const float inv = 1.0f / lh;
    const int d0 = (lane & 15) * 8;
    const size_t xo = (size_t)v * 128 + d0;

    float4 xv0 = *(const float4*)(x + xo);
    float4 xv1 = *(const float4*)(x + xo + 4);
    float4 bb0 = *(const float4*)(bias + d0);
    float4 bb1 = *(const float4*)(bias + d0 + 4);
    float xr8[8] = {xv0.x,xv0.y,xv0.z,xv0.w,xv1.x,xv1.y,xv1.z,xv1.w};
    float bi8[8] = {bb0.x,bb0.y,bb0.z,bb0.w,bb1.x,bb1.y,bb1.z,bb1.w};

    float y[8];
    float s = 0.f;
    #pragma unroll
    for (int k = 0; k < 8; ++k) {
        float o = acc[k] * inv;
        o += __shfl_xor(o, 16, 64);
        o += __shfl_xor(o, 32, 64);
        float yy = xr8[k] + o * 0.25f + bi8[k];
        y[k] = yy;
        s += yy;
    }
    s += __shfl_xor(s, 1, 64);
    s += __shfl_xor(s, 2, 64);
    s += __shfl_xor(s, 4, 64);
    s += __shfl_xor(s, 8, 64);
    float mu = s * (1.0f / 128.0f);
    float ss = 0.f;
    #pragma unroll
    for (int k = 0; k < 8; ++k) { float d = y[k] - mu; ss += d * d; }
    ss += __shfl_xor(ss, 1, 64);
    ss += __shfl_xor(ss, 2, 64);
    ss += __shfl_xor(ss, 4, 64);
    ss += __shfl_xor(ss, 8, 64);
    float rs = rsqrtf(ss * (1.0f / 128.0f) + LN_EPS);

    if ((lane >> 4) == 0) {                   // quarters hold identical y
        float4 g0 = *(const float4*)(g1 + d0);
        float4 g4 = *(const float4*)(g1 + d0 + 4);
        float4 e0 = *(const float4*)(be1 + d0);
        float4 e4 = *(const float4*)(be1 + d0 + 4);
        float gg[8] = {g0.x,g0.y,g0.z,g0.w,g4.x,g4.y,g4.z,g4.w};
        float ee[8] = {e0.x,e0.y,e0.z,e0.w,e4.x,e4.y,e4.z,e4.w};
        float z[8];
        #pragma unroll
        for (int k = 0; k < 8; ++k) z[k] = (y[k] - mu) * rs * gg[k] + ee[k];
        ushort4 zb0, zb1;
        zb0.x=f2bf(z[0]); zb0.y=f2bf(z[1]); zb0.z=f2bf(z[2]); zb0.w=f2bf(z[3]);
        zb1.x=f2bf(z[4]); zb1.y=f2bf(z[5]); zb1.z=f2bf(z[6]); zb1.w=f2bf(z[7]);
        *(ushort4*)(x1b + xo)     = zb0;
        *(ushort4*)(x1b + xo + 4) = zb1;
    }
}

// ---------------------------------------------------------------------------
// Fused FFN: h = GELU(x1b@W1^T+b1); f = h@W2^T+b2; out = LN2(x1b + f).
// Hidden tile lives in LDS (Ts). Per block: 128 nodes, self-contained.
// ---------------------------------------------------------------------------
__global__ __launch_bounds__(256) void ffn_fused(
    const ushort* __restrict__ x1b, const ushort* __restrict__ w1b,
    const float* __restrict__ b1, const ushort* __restrict__ w2b,
    const float* __restrict__ b2, const float* __restrict__ g2,
    const float* __restrict__ be2, float* __restrict__ out)
{
    __shared__ ushort As[128 * 128];   // x1b tile       32 KB
    __shared__ ushort Bs[128 * 128];   // weight tile    32 KB
    __shared__ ushort Ts[128 * 128];   // hidden half    32 KB
    const int tid  = threadIdx.x;
    const int rb   = blockIdx.x * 128;
    const int wave = tid >> 6, lane = tid & 63;
    const int wm   = (wave >> 1) * 64, wn = (wave & 1) * 64;
    const int lr   = lane & 15, lq = lane >> 4;

    #pragma unroll
    for (int i = 0; i < 8; ++i) {
        int chunk = tid + i * 256;
        int rr = chunk >> 4, cc = chunk & 15;
        int gr = rb + rr;
        uint4 va = make_uint4(0u,0u,0u,0u);
        if (gr < N_NODES) va = *(const uint4*)(x1b + (size_t)gr * 128 + cc * 8);
        *(uint4*)(As + rr * 128 + ((cc ^ (rr & 15)) * 8)) = va;
    }

    f32x4 zero = {0.f,0.f,0.f,0.f};
    f32x4 acc2[4][4];
    #pragma unroll
    for (int i = 0; i < 4; ++i)
        #pragma unroll
        for (int j = 0; j < 4; ++j) acc2[i][j] = zero;

    for (int half = 0; half < 2; ++half) {
        __syncthreads();
        // stage W1 half
        #pragma unroll
        for (int i = 0; i < 8; ++i) {
            int chunk = tid + i * 256;
            int rr = chunk >> 4, cc = chunk & 15;
            uint4 vb = *(const uint4*)(w1b + (size_t)(half * 128 + rr) * 128 + cc * 8);
            *(uint4*)(Bs + rr * 128 + ((cc ^ (rr & 15)) * 8)) = vb;
        }
        __syncthreads();

        f32x4 acc1[4][4];
        #pragma unroll
        for (int i = 0; i < 4; ++i)
            #pragma unroll
            for (int j = 0; j < 4; ++j) acc1[i][j] = zero;

        #pragma unroll
        for (int q = 0; q < 4; ++q) {
            int csw = ((q * 4 + lq) ^ lr) * 8;
            bf16x8 bfr[4], af[4];
            #pragma unroll
            for (int i = 0; i < 4; ++i) {
                bfr[i] = *(const bf16x8*)(Bs + (wm + i * 16 + lr) * 128 + csw);
                af[i]  = *(const bf16x8*)(As + (wn + i * 16 + lr) * 128 + csw);
            }
            #pragma unroll
            for (int i = 0; i < 4; ++i)
                #pragma unroll
                for (int j = 0; j < 4; ++j)
                    acc1[i][j] = __builtin_amdgcn_mfma_f32_16x16x32_bf16(
                        bfr[i], af[j], acc1[i][j], 0, 0, 0);
        }

        // GELU + write hidden to Ts (node-major, swizzled)
        #pragma unroll
        for (int i = 0; i < 4; ++i) {
            int wc = wm + i * 16 + lq * 4;
            float4 bv = *(const float4*)(b1 + half * 128 + wc);
            #pragma unroll
            for (int j = 0; j < 4; ++j) {
                int nl = wn + j * 16 + lr;
                float v0 = acc1[i][j][0] + bv.x;
                float v1 = acc1[i][j][1] + bv.y;
                float v2 = acc1[i][j][2] + bv.z;
                float v3 = acc1[i][j][3] + bv.w;
                v0 = v0 * 0.5f * (1.0f + erff(v0 * 0.70710678118654752f));
                v1 = v1 * 0.5f * (1.0f + erff(v1 * 0.70710678118654752f));
                v2 = v2 * 0.5f * (1.0f + erff(v2 * 0.70710678118654752f));
                v3 = v3 * 0.5f * (1.0f + erff(v3 * 0.70710678118654752f));
                ushort4 o;
                o.x = f2bf(v0); o.y = f2bf(v1); o.z = f2bf(v2); o.w = f2bf(v3);
                int sw = (((wc >> 3) ^ (nl & 15)) * 8) + (wc & 7);
                *(ushort4*)(Ts + nl * 128 + sw) = o;
            }
        }
        __syncthreads();
        // stage W2 K-slice
        #pragma unroll
        for (int i = 0; i < 8; ++i) {
            int chunk = tid + i * 256;
            int rr = chunk >> 4, cc = chunk & 15;
            uint4 vb = *(const uint4*)(w2b + (size_t)rr * 256 + half * 128 + cc * 8);
            *(uint4*)(Bs + rr * 128 + ((cc ^ (rr & 15)) * 8)) = vb;
        }
        __syncthreads();

        #pragma unroll
        for (int q = 0; q < 4; ++q) {
            int csw = ((q * 4 + lq) ^ lr) * 8;
            bf16x8 bfr[4], af[4];
            #pragma unroll
            for (int i = 0; i < 4; ++i) {
                bfr[i] = *(const bf16x8*)(Bs + (wm + i * 16 + lr) * 128 + csw);
                af[i]  = *(const bf16x8*)(Ts + (wn + i * 16 + lr) * 128 + csw);
            }
            #pragma unroll
            for (int i = 0; i < 4; ++i)
                #pragma unroll
                for (int j = 0; j < 4; ++j)
                    acc2[i][j] = __builtin_amdgcn_mfma_f32_16x16x32_bf16(
                        bfr[i], af[j], acc2[i][j], 0, 0, 0);
        }
    }

    __syncthreads();                          // As reusable for stats
    float* sums = (float*)As;                 // [2][128]
    float* ssqs = (float*)(As + 2048);        // [2][128]

    #pragma unroll
    for (int j = 0; j < 4; ++j) {
        int node = rb + wn + j * 16 + lr;
        float s = 0.f, q2 = 0.f;
        #pragma unroll
        for (int i = 0; i < 4; ++i) {
            int wc = wm + i * 16 + lq * 4;
            float4 bv = *(const float4*)(b2 + wc);
            float x0 = 0.f, x1r = 0.f, x2 = 0.f, x3 = 0.f;
            if (node < N_NODES) {
                ushort4 xv = *(const ushort4*)(x1b + (size_t)node * 128 + wc);
                x0 = bfu(&xv.x); x1r = bfu(&xv.y); x2 = bfu(&xv.z); x3 = bfu(&xv.w);
            }
            float y0 = acc2[i][j][0] + bv.x + x0;
            float y1 = acc2[i][j][1] + bv.y + x1r;
            float y2 = acc2[i][j][2] + bv.z + x2;
            float y3 = acc2[i][j][3] + bv.w + x3;
            acc2[i][j][0] = y0; acc2[i][j][1] = y1;
            acc2[i][j][2] = y2; acc2[i][j][3] = y3;
            s  += y0 + y1 + y2 + y3;
            q2 += y0*y0 + y1*y1 + y2*y2 + y3*y3;
        }
        s  += __shfl_xor(s, 16, 64);  s  += __shfl_xor(s, 32, 64);
        q2 += __shfl_xor(q2, 16, 64); q2 += __shfl_xor(q2, 32, 64);
        if (lq == 0) {
            int half = wm >> 6;
            sums[half * 128 + wn + j * 16 + lr] = s;
            ssqs[half * 128 + wn + j * 16 + lr] = q2;
        }
    }
    __syncthreads();

    #pragma unroll
    for (int j = 0; j < 4; ++j) {
        int nl = wn + j * 16 + lr;
        int node = rb + nl;
        if (node >= N_NODES) continue;
        float tot = sums[nl] + sums[128 + nl];
        float tq  = ssqs[nl] + ssqs[128 + nl];
        float mu  = tot * (1.0f / 128.0f);
        float var = tq * (1.0f / 128.0f) - mu * mu;
        float rs  = rsqrtf(var + LN_EPS);
        #pragma unroll
        for (int i = 0; i < 4; ++i) {
            int wc = wm + i * 16 + lq * 4;
            float4 gv = *(const float4*)(g2 + wc);
            float4 ev = *(const float4*)(be2 + wc);
            float4 o;
            o.x = (acc2[i][j][0] - mu) * rs * gv.x + ev.x;
            o.y = (acc2[i][j][1] - mu) * rs * gv.y + ev.y;
            o.z = (acc2[i][j][2] - mu) * rs * gv.z + ev.z;
            o.w = (acc2[i][j][3] - mu) * rs * gv.w + ev.w;
            *(float4*)(out + (size_t)node * 128 + wc) = o;
        }
    }
}

// ---------------------------------------------------------------------------
extern "C" void kernel_launch(void* const* d_in, const int* in_sizes, int n_in,
                              void* d_out, int out_size, void* d_ws, size_t ws_size,
                              hipStream_t stream)
{
    const float* x    = (const float*)d_in[0];
    const int*   ei   = (const int*)  d_in[1];
    const float* Wl   = (const float*)d_in[2];
    const float* bl   = (const float*)d_in[3];
    const float* Wr   = (const float*)d_in[4];
    const float* br   = (const float*)d_in[5];
    const float* att  = (const float*)d_in[6];
    const float* bias = (const float*)d_in[7];
    const float* g1   = (const float*)d_in[8];
    const float* be1  = (const float*)d_in[9];
    const float* W1   = (const float*)d_in[10];
    const float* b1   = (const float*)d_in[11];
    const float* W2   = (const float*)d_in[12];
    const float* b2   = (const float*)d_in[13];
    const float* g2   = (const float*)d_in[14];
    const float* be2  = (const float*)d_in[15];
    float* out = (float*)d_out;

    char* ws = (char*)d_ws;
    size_t off = 0;
    auto alloc = [&](size_t bytes) -> void* {
        void* p = ws + off;
        off = (off + bytes + 255) & ~(size_t)255;
        return p;
    };
    ushort* xlb  = (ushort*)alloc((size_t)N_NODES * 512 * 2);
    ushort* xrb  = (ushort*)alloc((size_t)N_NODES * 512 * 2);
    ushort* x1b  = (ushort*)alloc((size_t)N_NODES * 128 * 2);
    ushort* wb   = (ushort*)alloc((size_t)197120 * 2);
    int*   offs    = (int*)alloc((size_t)(N_NODES + 1) * 4);
    int*   counts  = (int*)alloc((size_t)N_NODES * 4 * 2);
    int*   cursor  = counts + N_NODES;
    int*   csum    = (int*)alloc(512);
    int*   srcList = (int*)alloc((size_t)EN_TOT * 4);

    ushort* wcat = wb;              // [Wl;Wr] 1024x128
    ushort* w1b  = wb + 131072;
    ushort* w2b  = wb + 163840;
    ushort* attb = wb + 196608;

    hipMemsetAsync(counts, 0, (size_t)N_NODES * 8, stream);

    cast_weights<<<770, 256, 0, stream>>>(Wl, Wr, W1, W2, att, wb);

    gemm_lr<<<dim3(391, 2), 256, 0, stream>>>(x, wcat, bl, br, xlb, xrb);

    count_deg<<<(EN_TOT + 255) / 256, 256, 0, stream>>>(ei + N_EDGES, counts);
    scan1<<<NC_SCAN, 64, 0, stream>>>(counts, csum);
    scan2<<<1, 64, 0, stream>>>(csum, offs);
    scan3<<<NC_SCAN, 64, 0, stream>>>(counts, csum, offs);
    scatter_edges<<<(EN_TOT + 255) / 256, 256, 0, stream>>>(ei, ei + N_EDGES,
                                                           offs, cursor, srcList);

    gat_fused<<<12500, 256, 0, stream>>>(x, xlb, xrb, offs, srcList, attb,
                                         bias, g1, be1, x1b);

    ffn_fused<<<391, 256, 0, stream>>>(x1b, w1b, b1, w2b, b2, g2, be2, out);
}

// Round 6
// 322.769 us; speedup vs baseline: 1.2916x; 1.0401x over previous
//
#include <hip/hip_runtime.h>
#include <cstdint>
#include <cstddef>

#define N_NODES 50000
#define N_EDGES 400000
#define EN_TOT  (N_EDGES + N_NODES)
#define NC_SCAN ((N_NODES + 511) / 512)   // 98
#define NEG_SLOPE 0.2f
#define LN_EPS 1e-5f

typedef short bf16x8 __attribute__((ext_vector_type(8)));
typedef float f32x4  __attribute__((ext_vector_type(4)));

__device__ __forceinline__ ushort f2bf(float f) {
    union { float f; uint32_t u; } c; c.f = f;
    uint32_t u = c.u + 0x7FFFu + ((c.u >> 16) & 1u);   // RNE
    return (ushort)(u >> 16);
}
__device__ __forceinline__ uint32_t pk2(float a, float b) {
    return (uint32_t)f2bf(a) | ((uint32_t)f2bf(b) << 16);
}
__device__ __forceinline__ float bf_lo(uint32_t u) {
    union { uint32_t u; float f; } c; c.u = u << 16; return c.f;
}
__device__ __forceinline__ float bf_hi(uint32_t u) {
    union { uint32_t u; float f; } c; c.u = u & 0xFFFF0000u; return c.f;
}
__device__ __forceinline__ float bfu(const ushort* p) {
    union { uint32_t u; float f; } c; c.u = ((uint32_t)*p) << 16; return c.f;
}

// ---------------------------------------------------------------------------
// prep: weights -> bf16 AND zero counts/cursor/scan-state (replaces memset).
// wb: [Wl 65536 | Wr 65536 | W1 32768 | W2 32768 | att 512]
// ---------------------------------------------------------------------------
__global__ __launch_bounds__(256) void prep(
    const float* __restrict__ Wl, const float* __restrict__ Wr,
    const float* __restrict__ W1, const float* __restrict__ W2,
    const float* __restrict__ att, ushort* __restrict__ wb,
    int* __restrict__ counts2 /*100000 ints*/, int* __restrict__ state /*256 ints*/)
{
    int i = blockIdx.x * 256 + threadIdx.x;          // 770*256 == 197120 exact
    const float* src; int off;
    if (i < 65536)       { src = Wl;  off = i; }
    else if (i < 131072) { src = Wr;  off = i - 65536; }
    else if (i < 163840) { src = W1;  off = i - 131072; }
    else if (i < 196608) { src = W2;  off = i - 163840; }
    else                 { src = att; off = i - 196608; }
    wb[i] = f2bf(src[off]);
    if (i < 100000) counts2[i] = 0;
    if (i < 256)    state[i] = 0;
}

// ---------------------------------------------------------------------------
// xl/xr GEMM (R3 form). A = x (fp32 -> bf16 while staging), stationary.
// 8 col-tiles of Wcat=[Wl;Wr]. Transposed MFMA -> ushort4 stores.
// ---------------------------------------------------------------------------
__global__ __launch_bounds__(256) void gemm_lr(
    const float* __restrict__ x, const ushort* __restrict__ wcat,
    const float* __restrict__ bl, const float* __restrict__ br,
    ushort* __restrict__ xlb, ushort* __restrict__ xrb)
{
    __shared__ ushort As[128 * 128];
    __shared__ ushort Bs[128 * 128];
    const int tid  = threadIdx.x;
    const int rb   = blockIdx.x * 128;
    const int wave = tid >> 6, lane = tid & 63;
    const int wm   = (wave >> 1) * 64, wn = (wave & 1) * 64;
    const int lr   = lane & 15, lq = lane >> 4;

    #pragma unroll
    for (int i = 0; i < 8; ++i) {
        int chunk = tid + i * 256;          // 0..2047
        int rr = chunk >> 4, cc = chunk & 15;
        int gr = rb + rr;
        float4 v0 = make_float4(0.f,0.f,0.f,0.f), v1 = v0;
        if (gr < N_NODES) {
            v0 = *(const float4*)(x + (size_t)gr * 128 + cc * 8);
            v1 = *(const float4*)(x + (size_t)gr * 128 + cc * 8 + 4);
        }
        uint4 h = make_uint4(pk2(v0.x,v0.y), pk2(v0.z,v0.w),
                             pk2(v1.x,v1.y), pk2(v1.z,v1.w));
        *(uint4*)(As + rr * 128 + ((cc ^ (rr & 15)) * 8)) = h;
    }

    for (int cbk = 0; cbk < 8; ++cbk) {
        __syncthreads();
        #pragma unroll
        for (int i = 0; i < 8; ++i) {
            int chunk = tid + i * 256;
            int rr = chunk >> 4, cc = chunk & 15;
            uint4 vb = *(const uint4*)(wcat + (size_t)(cbk * 128 + rr) * 128 + cc * 8);
            *(uint4*)(Bs + rr * 128 + ((cc ^ (rr & 15)) * 8)) = vb;
        }
        __syncthreads();

        f32x4 zero = {0.f,0.f,0.f,0.f};
        f32x4 acc[4][4];
        #pragma unroll
        for (int i = 0; i < 4; ++i)
            #pragma unroll
            for (int j = 0; j < 4; ++j) acc[i][j] = zero;

        #pragma unroll
        for (int q = 0; q < 4; ++q) {
            int csw = ((q * 4 + lq) ^ lr) * 8;
            bf16x8 bfr[4], af[4];
            #pragma unroll
            for (int i = 0; i < 4; ++i) {
                bfr[i] = *(const bf16x8*)(Bs + (wm + i * 16 + lr) * 128 + csw);
                af[i]  = *(const bf16x8*)(As + (wn + i * 16 + lr) * 128 + csw);
            }
            #pragma unroll
            for (int i = 0; i < 4; ++i)
                #pragma unroll
                for (int j = 0; j < 4; ++j)
                    acc[i][j] = __builtin_amdgcn_mfma_f32_16x16x32_bf16(
                        bfr[i], af[j], acc[i][j], 0, 0, 0);
        }

        const float* bias = (cbk < 4) ? bl : br;
        ushort* outp = (cbk < 4) ? xlb : xrb;
        const int cloc = (cbk & 3) * 128;
        #pragma unroll
        for (int i = 0; i < 4; ++i) {
            int wc = wm + i * 16 + lq * 4;
            float4 bv = *(const float4*)(bias + cloc + wc);
            #pragma unroll
            for (int j = 0; j < 4; ++j) {
                int node = rb + wn + j * 16 + lr;
                if (node < N_NODES) {
                    ushort4 o;
                    o.x = f2bf(acc[i][j][0] + bv.x);
                    o.y = f2bf(acc[i][j][1] + bv.y);
                    o.z = f2bf(acc[i][j][2] + bv.z);
                    o.w = f2bf(acc[i][j][3] + bv.w);
                    *(ushort4*)(outp + (size_t)node * 512 + cloc + wc) = o;
                }
            }
        }
    }
}

// ---------------------------------------------------------------------------
// CSR build: count -> single-dispatch decoupled-lookback scan -> scatter
// ---------------------------------------------------------------------------
__global__ __launch_bounds__(256) void count_deg(const int* __restrict__ dst,
                                                 int* __restrict__ counts)
{
    int i = blockIdx.x * 256 + threadIdx.x;
    if (i >= EN_TOT) return;
    int d = (i < N_EDGES) ? dst[i] : (i - N_EDGES);
    atomicAdd(counts + d, 1);
}

// 98 single-wave blocks; all co-resident (98 < 256 CUs) so spin is safe.
// All cross-block state is inside one 64-bit atomic: flag(<<32) | value.
__global__ __launch_bounds__(64) void scan_lb(const int* __restrict__ counts,
                                              int* __restrict__ offs,
                                              unsigned long long* __restrict__ state)
{
    const int b = blockIdx.x, lane = threadIdx.x;
    const int base = b * 512 + lane * 8;
    int cnt[8];
    int s = 0;
    #pragma unroll
    for (int k = 0; k < 8; ++k) {
        int idx = base + k;
        cnt[k] = (idx < N_NODES) ? counts[idx] : 0;
        s += cnt[k];
    }
    int inc = s;                              // inclusive wave scan
    #pragma unroll
    for (int d = 1; d < 64; d <<= 1) {
        int t = __shfl_up(inc, d, 64);
        if (lane >= d) inc += t;
    }
    const int total = __shfl(inc, 63, 64);

    if (lane == 0) {
        unsigned long long pub = ((unsigned long long)(b == 0 ? 2u : 1u) << 32)
                               | (unsigned)total;
        atomicExch(&state[b], pub);
    }

    int prefix = 0;
    if (b > 0) {
        int p0 = b - 1;
        while (true) {
            int p = p0 - lane;
            int flag, val;
            if (p >= 0) {
                unsigned long long v;
                do { v = atomicAdd(&state[p], 0ULL); flag = (int)(v >> 32); }
                while (flag == 0);
                val = (int)(unsigned)v;
            } else { flag = 2; val = 0; }
            unsigned long long mask = __ballot(flag == 2);
            int L = mask ? (__ffsll(mask) - 1) : 64;
            int take = (lane <= L) ? val : 0;
            #pragma unroll
            for (int m = 32; m; m >>= 1) take += __shfl_xor(take, m, 64);
            prefix += take;
            if (L < 64) break;
            p0 -= 64;
        }
        if (lane == 0)
            atomicExch(&state[b], (2ULL << 32) | (unsigned)(prefix + total));
    }

    int run = prefix + inc - s;               // exclusive start for this lane
    #pragma unroll
    for (int k = 0; k < 8; ++k) {
        int idx = base + k;
        if (idx < N_NODES) { offs[idx] = run; run += cnt[k]; }
    }
    if (b == NC_SCAN - 1 && lane == 63) offs[N_NODES] = prefix + inc;  // == EN_TOT
}

__global__ __launch_bounds__(256) void scatter_edges(
    const int* __restrict__ src, const int* __restrict__ dst,
    const int* __restrict__ offs, int* __restrict__ cursor,
    int* __restrict__ srcList)
{
    int i = blockIdx.x * 256 + threadIdx.x;
    if (i >= EN_TOT) return;
    int s, d;
    if (i < N_EDGES) { s = src[i]; d = dst[i]; }
    else             { s = d = i - N_EDGES; }
    int pos = atomicAdd(cursor + d, 1);
    srcList[offs[d] + pos] = s;
}

// ---------------------------------------------------------------------------
// GATv2 per destination node (one wave each), bf16 gather, prefetch-1 loop
// (R3 form — best measured). + head-mean + bias + residual + LN1 -> x1b.
// ---------------------------------------------------------------------------
__global__ __launch_bounds__(256) void gat_fused(
    const float* __restrict__ x, const ushort* __restrict__ xl,
    const ushort* __restrict__ xr, const int* __restrict__ offs,
    const int* __restrict__ srcList, const ushort* __restrict__ attb,
    const float* __restrict__ bias, const float* __restrict__ g1,
    const float* __restrict__ be1, ushort* __restrict__ x1b)
{
    const int wave = threadIdx.x >> 6;
    const int lane = threadIdx.x & 63;
    const int v = blockIdx.x * 4 + wave;
    if (v >= N_NODES) return;

    uint4 rw = *(const uint4*)(xr + (size_t)v * 512 + lane * 8);
    uint4 aw = *(const uint4*)(attb + lane * 8);
    float r[8], at[8];
    r[0]=bf_lo(rw.x); r[1]=bf_hi(rw.x); r[2]=bf_lo(rw.y); r[3]=bf_hi(rw.y);
    r[4]=bf_lo(rw.z); r[5]=bf_hi(rw.z); r[6]=bf_lo(rw.w); r[7]=bf_hi(rw.w);
    at[0]=bf_lo(aw.x); at[1]=bf_hi(aw.x); at[2]=bf_lo(aw.y); at[3]=bf_hi(aw.y);
    at[4]=bf_lo(aw.z); at[5]=bf_hi(aw.z); at[6]=bf_lo(aw.w); at[7]=bf_hi(aw.w);

    float acc[8] = {0.f,0.f,0.f,0.f,0.f,0.f,0.f,0.f};
    float lh = 0.f;

    const int jb = offs[v], je = offs[v + 1];
    uint4 cur = *(const uint4*)(xl + (size_t)srcList[jb] * 512 + lane * 8);
    for (int j = jb; j < je; ++j) {
        int jn = (j + 1 < je) ? (j + 1) : j;
        uint4 nxt = *(const uint4*)(xl + (size_t)srcList[jn] * 512 + lane * 8);

        float b[8];
        b[0]=bf_lo(cur.x); b[1]=bf_hi(cur.x); b[2]=bf_lo(cur.y); b[3]=bf_hi(cur.y);
        b[4]=bf_lo(cur.z); b[5]=bf_hi(cur.z); b[6]=bf_lo(cur.w); b[7]=bf_hi(cur.w);
        float p = 0.f;
        #pragma unroll
        for (int k = 0; k < 8; ++k) {
            float s  = b[k] + r[k];
            float lr2 = fmaxf(s, 0.f) + NEG_SLOPE * fminf(s, 0.f);
            p = fmaf(lr2, at[k], p);
        }
        p += __shfl_xor(p, 1, 64);
        p += __shfl_xor(p, 2, 64);
        p += __shfl_xor(p, 4, 64);
        p += __shfl_xor(p, 8, 64);
        float w = __expf(p);
        lh += w;
        #pragma unroll
        for (int k = 0; k < 8; ++k) acc[k] = fmaf(w, b[k], acc[k]);
        cur = nxt;
    }

    const float inv = 1.0f / lh;
    const int d0 = (lane & 15) * 8;
    const size_t xo = (size_t)v * 128 + d0;

    float4 xv0 = *(const float4*)(x + xo);
    float4 xv1 = *(const float4*)(x + xo + 4);
    float4 bb0 = *(const float4*)(bias + d0);
    float4 bb1 = *(const float4*)(bias + d0 + 4);
    float xr8[8] = {xv0.x,xv0.y,xv0.z,xv0.w,xv1.x,xv1.y,xv1.z,xv1.w};
    float bi8[8] = {bb0.x,bb0.y,bb0.z,bb0.w,bb1.x,bb1.y,bb1.z,bb1.w};

    float y[8];
    float s = 0.f;
    #pragma unroll
    for (int k = 0; k < 8; ++k) {
        float o = acc[k] * inv;
        o += __shfl_xor(o, 16, 64);
        o += __shfl_xor(o, 32, 64);
        float yy = xr8[k] + o * 0.25f + bi8[k];
        y[k] = yy;
        s += yy;
    }
    s += __shfl_xor(s, 1, 64);
    s += __shfl_xor(s, 2, 64);
    s += __shfl_xor(s, 4, 64);
    s += __shfl_xor(s, 8, 64);
    float mu = s * (1.0f / 128.0f);
    float ss = 0.f;
    #pragma unroll
    for (int k = 0; k < 8; ++k) { float d = y[k] - mu; ss += d * d; }
    ss += __shfl_xor(ss, 1, 64);
    ss += __shfl_xor(ss, 2, 64);
    ss += __shfl_xor(ss, 4, 64);
    ss += __shfl_xor(ss, 8, 64);
    float rs = rsqrtf(ss * (1.0f / 128.0f) + LN_EPS);

    if ((lane >> 4) == 0) {                   // quarters hold identical y
        float4 g0 = *(const float4*)(g1 + d0);
        float4 g4 = *(const float4*)(g1 + d0 + 4);
        float4 e0 = *(const float4*)(be1 + d0);
        float4 e4 = *(const float4*)(be1 + d0 + 4);
        float gg[8] = {g0.x,g0.y,g0.z,g0.w,g4.x,g4.y,g4.z,g4.w};
        float ee[8] = {e0.x,e0.y,e0.z,e0.w,e4.x,e4.y,e4.z,e4.w};
        float z[8];
        #pragma unroll
        for (int k = 0; k < 8; ++k) z[k] = (y[k] - mu) * rs * gg[k] + ee[k];
        ushort4 zb0, zb1;
        zb0.x=f2bf(z[0]); zb0.y=f2bf(z[1]); zb0.z=f2bf(z[2]); zb0.w=f2bf(z[3]);
        zb1.x=f2bf(z[4]); zb1.y=f2bf(z[5]); zb1.z=f2bf(z[6]); zb1.w=f2bf(z[7]);
        *(ushort4*)(x1b + xo)     = zb0;
        *(ushort4*)(x1b + xo + 4) = zb1;
    }
}

// ---------------------------------------------------------------------------
// Fused FFN: h = GELU(x1b@W1^T+b1); f = h@W2^T+b2; out = LN2(x1b + f).
// ---------------------------------------------------------------------------
__global__ __launch_bounds__(256) void ffn_fused(
    const ushort* __restrict__ x1b, const ushort* __restrict__ w1b,
    const float* __restrict__ b1, const ushort* __restrict__ w2b,
    const float* __restrict__ b2, const float* __restrict__ g2,
    const float* __restrict__ be2, float* __restrict__ out)
{
    __shared__ ushort As[128 * 128];   // x1b tile       32 KB
    __shared__ ushort Bs[128 * 128];   // weight tile    32 KB
    __shared__ ushort Ts[128 * 128];   // hidden half    32 KB
    const int tid  = threadIdx.x;
    const int rb   = blockIdx.x * 128;
    const int wave = tid >> 6, lane = tid & 63;
    const int wm   = (wave >> 1) * 64, wn = (wave & 1) * 64;
    const int lr   = lane & 15, lq = lane >> 4;

    #pragma unroll
    for (int i = 0; i < 8; ++i) {
        int chunk = tid + i * 256;
        int rr = chunk >> 4, cc = chunk & 15;
        int gr = rb + rr;
        uint4 va = make_uint4(0u,0u,0u,0u);
        if (gr < N_NODES) va = *(const uint4*)(x1b + (size_t)gr * 128 + cc * 8);
        *(uint4*)(As + rr * 128 + ((cc ^ (rr & 15)) * 8)) = va;
    }

    f32x4 zero = {0.f,0.f,0.f,0.f};
    f32x4 acc2[4][4];
    #pragma unroll
    for (int i = 0; i < 4; ++i)
        #pragma unroll
        for (int j = 0; j < 4; ++j) acc2[i][j] = zero;

    for (int half = 0; half < 2; ++half) {
        __syncthreads();
        #pragma unroll
        for (int i = 0; i < 8; ++i) {
            int chunk = tid + i * 256;
            int rr = chunk >> 4, cc = chunk & 15;
            uint4 vb = *(const uint4*)(w1b + (size_t)(half * 128 + rr) * 128 + cc * 8);
            *(uint4*)(Bs + rr * 128 + ((cc ^ (rr & 15)) * 8)) = vb;
        }
        __syncthreads();

        f32x4 acc1[4][4];
        #pragma unroll
        for (int i = 0; i < 4; ++i)
            #pragma unroll
            for (int j = 0; j < 4; ++j) acc1[i][j] = zero;

        #pragma unroll
        for (int q = 0; q < 4; ++q) {
            int csw = ((q * 4 + lq) ^ lr) * 8;
            bf16x8 bfr[4], af[4];
            #pragma unroll
            for (int i = 0; i < 4; ++i) {
                bfr[i] = *(const bf16x8*)(Bs + (wm + i * 16 + lr) * 128 + csw);
                af[i]  = *(const bf16x8*)(As + (wn + i * 16 + lr) * 128 + csw);
            }
            #pragma unroll
            for (int i = 0; i < 4; ++i)
                #pragma unroll
                for (int j = 0; j < 4; ++j)
                    acc1[i][j] = __builtin_amdgcn_mfma_f32_16x16x32_bf16(
                        bfr[i], af[j], acc1[i][j], 0, 0, 0);
        }

        #pragma unroll
        for (int i = 0; i < 4; ++i) {
            int wc = wm + i * 16 + lq * 4;
            float4 bv = *(const float4*)(b1 + half * 128 + wc);
            #pragma unroll
            for (int j = 0; j < 4; ++j) {
                int nl = wn + j * 16 + lr;
                float v0 = acc1[i][j][0] + bv.x;
                float v1 = acc1[i][j][1] + bv.y;
                float v2 = acc1[i][j][2] + bv.z;
                float v3 = acc1[i][j][3] + bv.w;
                v0 = v0 * 0.5f * (1.0f + erff(v0 * 0.70710678118654752f));
                v1 = v1 * 0.5f * (1.0f + erff(v1 * 0.70710678118654752f));
                v2 = v2 * 0.5f * (1.0f + erff(v2 * 0.70710678118654752f));
                v3 = v3 * 0.5f * (1.0f + erff(v3 * 0.70710678118654752f));
                ushort4 o;
                o.x = f2bf(v0); o.y = f2bf(v1); o.z = f2bf(v2); o.w = f2bf(v3);
                int sw = (((wc >> 3) ^ (nl & 15)) * 8) + (wc & 7);
                *(ushort4*)(Ts + nl * 128 + sw) = o;
            }
        }
        __syncthreads();
        #pragma unroll
        for (int i = 0; i < 8; ++i) {
            int chunk = tid + i * 256;
            int rr = chunk >> 4, cc = chunk & 15;
            uint4 vb = *(const uint4*)(w2b + (size_t)rr * 256 + half * 128 + cc * 8);
            *(uint4*)(Bs + rr * 128 + ((cc ^ (rr & 15)) * 8)) = vb;
        }
        __syncthreads();

        #pragma unroll
        for (int q = 0; q < 4; ++q) {
            int csw = ((q * 4 + lq) ^ lr) * 8;
            bf16x8 bfr[4], af[4];
            #pragma unroll
            for (int i = 0; i < 4; ++i) {
                bfr[i] = *(const bf16x8*)(Bs + (wm + i * 16 + lr) * 128 + csw);
                af[i]  = *(const bf16x8*)(Ts + (wn + i * 16 + lr) * 128 + csw);
            }
            #pragma unroll
            for (int i = 0; i < 4; ++i)
                #pragma unroll
                for (int j = 0; j < 4; ++j)
                    acc2[i][j] = __builtin_amdgcn_mfma_f32_16x16x32_bf16(
                        bfr[i], af[j], acc2[i][j], 0, 0, 0);
        }
    }

    __syncthreads();
    float* sums = (float*)As;                 // [2][128]
    float* ssqs = (float*)(As + 2048);        // [2][128]

    #pragma unroll
    for (int j = 0; j < 4; ++j) {
        int node = rb + wn + j * 16 + lr;
        float s = 0.f, q2 = 0.f;
        #pragma unroll
        for (int i = 0; i < 4; ++i) {
            int wc = wm + i * 16 + lq * 4;
            float4 bv = *(const float4*)(b2 + wc);
            float x0 = 0.f, x1r = 0.f, x2 = 0.f, x3 = 0.f;
            if (node < N_NODES) {
                ushort4 xv = *(const ushort4*)(x1b + (size_t)node * 128 + wc);
                x0 = bfu(&xv.x); x1r = bfu(&xv.y); x2 = bfu(&xv.z); x3 = bfu(&xv.w);
            }
            float y0 = acc2[i][j][0] + bv.x + x0;
            float y1 = acc2[i][j][1] + bv.y + x1r;
            float y2 = acc2[i][j][2] + bv.z + x2;
            float y3 = acc2[i][j][3] + bv.w + x3;
            acc2[i][j][0] = y0; acc2[i][j][1] = y1;
            acc2[i][j][2] = y2; acc2[i][j][3] = y3;
            s  += y0 + y1 + y2 + y3;
            q2 += y0*y0 + y1*y1 + y2*y2 + y3*y3;
        }
        s  += __shfl_xor(s, 16, 64);  s  += __shfl_xor(s, 32, 64);
        q2 += __shfl_xor(q2, 16, 64); q2 += __shfl_xor(q2, 32, 64);
        if (lq == 0) {
            int half = wm >> 6;
            sums[half * 128 + wn + j * 16 + lr] = s;
            ssqs[half * 128 + wn + j * 16 + lr] = q2;
        }
    }
    __syncthreads();

    #pragma unroll
    for (int j = 0; j < 4; ++j) {
        int nl = wn + j * 16 + lr;
        int node = rb + nl;
        if (node >= N_NODES) continue;
        float tot = sums[nl] + sums[128 + nl];
        float tq  = ssqs[nl] + ssqs[128 + nl];
        float mu  = tot * (1.0f / 128.0f);
        float var = tq * (1.0f / 128.0f) - mu * mu;
        float rs  = rsqrtf(var + LN_EPS);
        #pragma unroll
        for (int i = 0; i < 4; ++i) {
            int wc = wm + i * 16 + lq * 4;
            float4 gv = *(const float4*)(g2 + wc);
            float4 ev = *(const float4*)(be2 + wc);
            float4 o;
            o.x = (acc2[i][j][0] - mu) * rs * gv.x + ev.x;
            o.y = (acc2[i][j][1] - mu) * rs * gv.y + ev.y;
            o.z = (acc2[i][j][2] - mu) * rs * gv.z + ev.z;
            o.w = (acc2[i][j][3] - mu) * rs * gv.w + ev.w;
            *(float4*)(out + (size_t)node * 128 + wc) = o;
        }
    }
}

// ---------------------------------------------------------------------------
extern "C" void kernel_launch(void* const* d_in, const int* in_sizes, int n_in,
                              void* d_out, int out_size, void* d_ws, size_t ws_size,
                              hipStream_t stream)
{
    const float* x    = (const float*)d_in[0];
    const int*   ei   = (const int*)  d_in[1];
    const float* Wl   = (const float*)d_in[2];
    const float* bl   = (const float*)d_in[3];
    const float* Wr   = (const float*)d_in[4];
    const float* br   = (const float*)d_in[5];
    const float* att  = (const float*)d_in[6];
    const float* bias = (const float*)d_in[7];
    const float* g1   = (const float*)d_in[8];
    const float* be1  = (const float*)d_in[9];
    const float* W1   = (const float*)d_in[10];
    const float* b1   = (const float*)d_in[11];
    const float* W2   = (const float*)d_in[12];
    const float* b2   = (const float*)d_in[13];
    const float* g2   = (const float*)d_in[14];
    const float* be2  = (const float*)d_in[15];
    float* out = (float*)d_out;

    char* ws = (char*)d_ws;
    size_t off = 0;
    auto alloc = [&](size_t bytes) -> void* {
        void* p = ws + off;
        off = (off + bytes + 255) & ~(size_t)255;
        return p;
    };
    ushort* xlb  = (ushort*)alloc((size_t)N_NODES * 512 * 2);
    ushort* xrb  = (ushort*)alloc((size_t)N_NODES * 512 * 2);
    ushort* x1b  = (ushort*)alloc((size_t)N_NODES * 128 * 2);
    ushort* wb   = (ushort*)alloc((size_t)197120 * 2);
    int*   offs    = (int*)alloc((size_t)(N_NODES + 1) * 4);
    int*   counts  = (int*)alloc((size_t)N_NODES * 4 * 2);  // counts + cursor
    int*   cursor  = counts + N_NODES;
    unsigned long long* state = (unsigned long long*)alloc(256 * 4);
    int*   srcList = (int*)alloc((size_t)EN_TOT * 4);

    ushort* wcat = wb;              // [Wl;Wr] 1024x128
    ushort* w1b  = wb + 131072;
    ushort* w2b  = wb + 163840;
    ushort* attb = wb + 196608;

    prep<<<770, 256, 0, stream>>>(Wl, Wr, W1, W2, att, wb, counts, (int*)state);

    gemm_lr<<<391, 256, 0, stream>>>(x, wcat, bl, br, xlb, xrb);

    count_deg<<<(EN_TOT + 255) / 256, 256, 0, stream>>>(ei + N_EDGES, counts);
    scan_lb<<<NC_SCAN, 64, 0, stream>>>(counts, offs, state);
    scatter_edges<<<(EN_TOT + 255) / 256, 256, 0, stream>>>(ei, ei + N_EDGES,
                                                           offs, cursor, srcList);

    gat_fused<<<12500, 256, 0, stream>>>(x, xlb, xrb, offs, srcList, attb,
                                         bias, g1, be1, x1b);

    ffn_fused<<<391, 256, 0, stream>>>(x1b, w1b, b1, w2b, b2, g2, be2, out);
}

// Round 7
// 303.757 us; speedup vs baseline: 1.3724x; 1.0626x over previous
//
#include <hip/hip_runtime.h>
#include <cstdint>
#include <cstddef>

#define N_NODES 50000
#define N_EDGES 400000
#define EN_TOT  (N_EDGES + N_NODES)
#define NC_SCAN ((N_NODES + 511) / 512)   // 98
#define NEG_SLOPE 0.2f
#define LN_EPS 1e-5f

typedef short bf16x8 __attribute__((ext_vector_type(8)));
typedef float f32x4  __attribute__((ext_vector_type(4)));

__device__ __forceinline__ ushort f2bf(float f) {
    union { float f; uint32_t u; } c; c.f = f;
    uint32_t u = c.u + 0x7FFFu + ((c.u >> 16) & 1u);   // RNE
    return (ushort)(u >> 16);
}
__device__ __forceinline__ uint32_t pk2(float a, float b) {
    return (uint32_t)f2bf(a) | ((uint32_t)f2bf(b) << 16);
}
__device__ __forceinline__ float bf_lo(uint32_t u) {
    union { uint32_t u; float f; } c; c.u = u << 16; return c.f;
}
__device__ __forceinline__ float bf_hi(uint32_t u) {
    union { uint32_t u; float f; } c; c.u = u & 0xFFFF0000u; return c.f;
}
__device__ __forceinline__ float bfu(ushort v) {
    union { uint32_t u; float f; } c; c.u = ((uint32_t)v) << 16; return c.f;
}

// ---------------------------------------------------------------------------
// prep: weights -> bf16 AND zero counts/cursor/scan-state.
// wb: [Wl 65536 | Wr 65536 | W1 32768 | W2 32768 | att 512]
// ---------------------------------------------------------------------------
__global__ __launch_bounds__(256) void prep(
    const float* __restrict__ Wl, const float* __restrict__ Wr,
    const float* __restrict__ W1, const float* __restrict__ W2,
    const float* __restrict__ att, ushort* __restrict__ wb,
    int* __restrict__ counts2 /*100000 ints*/, int* __restrict__ state /*256 ints*/)
{
    int i = blockIdx.x * 256 + threadIdx.x;          // 770*256 == 197120 exact
    const float* src; int off;
    if (i < 65536)       { src = Wl;  off = i; }
    else if (i < 131072) { src = Wr;  off = i - 65536; }
    else if (i < 163840) { src = W1;  off = i - 131072; }
    else if (i < 196608) { src = W2;  off = i - 163840; }
    else                 { src = att; off = i - 196608; }
    wb[i] = f2bf(src[off]);
    if (i < 100000) counts2[i] = 0;
    if (i < 256)    state[i] = 0;
}

// ---------------------------------------------------------------------------
// xl/xr GEMM, A-stationary over 8 col-tiles of Wcat=[Wl;Wr].
// + folded-in degree counting (atomics overlap MFMA).
// Output restaged through LDS (stride-136 pad) -> coalesced 256B writes.
// ---------------------------------------------------------------------------
__global__ __launch_bounds__(256) void gemm_lr(
    const float* __restrict__ x, const ushort* __restrict__ wcat,
    const float* __restrict__ bl, const float* __restrict__ br,
    ushort* __restrict__ xlb, ushort* __restrict__ xrb,
    const int* __restrict__ dst, int* __restrict__ counts)
{
    __shared__ ushort As[128 * 128];   // 32 KB
    __shared__ ushort Bs[128 * 136];   // 34 KB (weights use stride 128; out restage stride 136)
    const int tid  = threadIdx.x;
    const int rb   = blockIdx.x * 128;
    const int wave = tid >> 6, lane = tid & 63;
    const int wm   = (wave >> 1) * 64, wn = (wave & 1) * 64;
    const int lr   = lane & 15, lq = lane >> 4;

    // folded count_deg: this block's slice of edges (391*1152 >= EN_TOT)
    {
        int e0 = blockIdx.x * 1152;
        int e1 = e0 + 1152; if (e1 > EN_TOT) e1 = EN_TOT;
        for (int e = e0 + tid; e < e1; e += 256) {
            int d = (e < N_EDGES) ? dst[e] : (e - N_EDGES);
            atomicAdd(counts + d, 1);
        }
    }

    #pragma unroll
    for (int i = 0; i < 8; ++i) {
        int chunk = tid + i * 256;          // 0..2047
        int rr = chunk >> 4, cc = chunk & 15;
        int gr = rb + rr;
        float4 v0 = make_float4(0.f,0.f,0.f,0.f), v1 = v0;
        if (gr < N_NODES) {
            v0 = *(const float4*)(x + (size_t)gr * 128 + cc * 8);
            v1 = *(const float4*)(x + (size_t)gr * 128 + cc * 8 + 4);
        }
        uint4 h = make_uint4(pk2(v0.x,v0.y), pk2(v0.z,v0.w),
                             pk2(v1.x,v1.y), pk2(v1.z,v1.w));
        *(uint4*)(As + rr * 128 + ((cc ^ (rr & 15)) * 8)) = h;
    }

    for (int cbk = 0; cbk < 8; ++cbk) {
        __syncthreads();                 // prev writeout done reading Bs / As ready
        #pragma unroll
        for (int i = 0; i < 8; ++i) {
            int chunk = tid + i * 256;
            int rr = chunk >> 4, cc = chunk & 15;
            uint4 vb = *(const uint4*)(wcat + (size_t)(cbk * 128 + rr) * 128 + cc * 8);
            *(uint4*)(Bs + rr * 128 + ((cc ^ (rr & 15)) * 8)) = vb;
        }
        __syncthreads();

        f32x4 zero = {0.f,0.f,0.f,0.f};
        f32x4 acc[4][4];
        #pragma unroll
        for (int i = 0; i < 4; ++i)
            #pragma unroll
            for (int j = 0; j < 4; ++j) acc[i][j] = zero;

        #pragma unroll
        for (int q = 0; q < 4; ++q) {
            int csw = ((q * 4 + lq) ^ lr) * 8;
            bf16x8 bfr[4], af[4];
            #pragma unroll
            for (int i = 0; i < 4; ++i) {
                bfr[i] = *(const bf16x8*)(Bs + (wm + i * 16 + lr) * 128 + csw);
                af[i]  = *(const bf16x8*)(As + (wn + i * 16 + lr) * 128 + csw);
            }
            #pragma unroll
            for (int i = 0; i < 4; ++i)
                #pragma unroll
                for (int j = 0; j < 4; ++j)
                    acc[i][j] = __builtin_amdgcn_mfma_f32_16x16x32_bf16(
                        bfr[i], af[j], acc[i][j], 0, 0, 0);
        }

        __syncthreads();                 // MFMA reads of Bs done -> restage output
        const float* bias = (cbk < 4) ? bl : br;
        ushort* outp = (cbk < 4) ? xlb : xrb;
        const int cloc = (cbk & 3) * 128;
        #pragma unroll
        for (int i = 0; i < 4; ++i) {
            int wc = wm + i * 16 + lq * 4;
            float4 bv = *(const float4*)(bias + cloc + wc);
            #pragma unroll
            for (int j = 0; j < 4; ++j) {
                int nl = wn + j * 16 + lr;
                ushort4 o;
                o.x = f2bf(acc[i][j][0] + bv.x);
                o.y = f2bf(acc[i][j][1] + bv.y);
                o.z = f2bf(acc[i][j][2] + bv.z);
                o.w = f2bf(acc[i][j][3] + bv.w);
                *(ushort4*)(Bs + nl * 136 + wc) = o;
            }
        }
        __syncthreads();
        // coalesced writeout: 16 lanes cover 256B contiguous
        #pragma unroll
        for (int i = 0; i < 8; ++i) {
            int chunk = tid + i * 256;     // 0..2047
            int row = chunk >> 4, cc = chunk & 15;
            int node = rb + row;
            if (node < N_NODES) {
                uint4 v = *(const uint4*)(Bs + row * 136 + cc * 8);
                *(uint4*)(outp + (size_t)node * 512 + cloc + cc * 8) = v;
            }
        }
    }
}

// ---------------------------------------------------------------------------
// CSR: single-dispatch decoupled-lookback scan -> scatter
// ---------------------------------------------------------------------------
__global__ __launch_bounds__(64) void scan_lb(const int* __restrict__ counts,
                                              int* __restrict__ offs,
                                              unsigned long long* __restrict__ state)
{
    const int b = blockIdx.x, lane = threadIdx.x;
    const int base = b * 512 + lane * 8;
    int cnt[8];
    int s = 0;
    #pragma unroll
    for (int k = 0; k < 8; ++k) {
        int idx = base + k;
        cnt[k] = (idx < N_NODES) ? counts[idx] : 0;
        s += cnt[k];
    }
    int inc = s;                              // inclusive wave scan
    #pragma unroll
    for (int d = 1; d < 64; d <<= 1) {
        int t = __shfl_up(inc, d, 64);
        if (lane >= d) inc += t;
    }
    const int total = __shfl(inc, 63, 64);

    if (lane == 0) {
        unsigned long long pub = ((unsigned long long)(b == 0 ? 2u : 1u) << 32)
                               | (unsigned)total;
        atomicExch(&state[b], pub);
    }

    int prefix = 0;
    if (b > 0) {
        int p0 = b - 1;
        while (true) {
            int p = p0 - lane;
            int flag, val;
            if (p >= 0) {
                unsigned long long v;
                do { v = atomicAdd(&state[p], 0ULL); flag = (int)(v >> 32); }
                while (flag == 0);
                val = (int)(unsigned)v;
            } else { flag = 2; val = 0; }
            unsigned long long mask = __ballot(flag == 2);
            int L = mask ? (__ffsll(mask) - 1) : 64;
            int take = (lane <= L) ? val : 0;
            #pragma unroll
            for (int m = 32; m; m >>= 1) take += __shfl_xor(take, m, 64);
            prefix += take;
            if (L < 64) break;
            p0 -= 64;
        }
        if (lane == 0)
            atomicExch(&state[b], (2ULL << 32) | (unsigned)(prefix + total));
    }

    int run = prefix + inc - s;
    #pragma unroll
    for (int k = 0; k < 8; ++k) {
        int idx = base + k;
        if (idx < N_NODES) { offs[idx] = run; run += cnt[k]; }
    }
    if (b == NC_SCAN - 1 && lane == 63) offs[N_NODES] = prefix + inc;
}

__global__ __launch_bounds__(256) void scatter_edges(
    const int* __restrict__ src, const int* __restrict__ dst,
    const int* __restrict__ offs, int* __restrict__ cursor,
    int* __restrict__ srcList)
{
    int i = blockIdx.x * 256 + threadIdx.x;
    if (i >= EN_TOT) return;
    int s, d;
    if (i < N_EDGES) { s = src[i]; d = dst[i]; }
    else             { s = d = i - N_EDGES; }
    int pos = atomicAdd(cursor + d, 1);
    srcList[offs[d] + pos] = s;
}

// ---------------------------------------------------------------------------
// GATv2 per destination node (one wave each), bf16 gather, prefetch depth 3
// to raise achieved random-gather BW (gat is BW-bound: dur == bytes/BW).
// + head-mean + bias + residual + LN1 -> x1b.
// ---------------------------------------------------------------------------
__global__ __launch_bounds__(256) void gat_fused(
    const float* __restrict__ x, const ushort* __restrict__ xl,
    const ushort* __restrict__ xr, const int* __restrict__ offs,
    const int* __restrict__ srcList, const ushort* __restrict__ attb,
    const float* __restrict__ bias, const float* __restrict__ g1,
    const float* __restrict__ be1, ushort* __restrict__ x1b)
{
    const int wave = threadIdx.x >> 6;
    const int lane = threadIdx.x & 63;
    const int v = blockIdx.x * 4 + wave;
    if (v >= N_NODES) return;

    uint4 rw = *(const uint4*)(xr + (size_t)v * 512 + lane * 8);
    uint4 aw = *(const uint4*)(attb + lane * 8);
    float r[8], at[8];
    r[0]=bf_lo(rw.x); r[1]=bf_hi(rw.x); r[2]=bf_lo(rw.y); r[3]=bf_hi(rw.y);
    r[4]=bf_lo(rw.z); r[5]=bf_hi(rw.z); r[6]=bf_lo(rw.w); r[7]=bf_hi(rw.w);
    at[0]=bf_lo(aw.x); at[1]=bf_hi(aw.x); at[2]=bf_lo(aw.y); at[3]=bf_hi(aw.y);
    at[4]=bf_lo(aw.z); at[5]=bf_hi(aw.z); at[6]=bf_lo(aw.w); at[7]=bf_hi(aw.w);

    float acc[8] = {0.f,0.f,0.f,0.f,0.f,0.f,0.f,0.f};
    float lh = 0.f;

    const int jb = offs[v], je = offs[v + 1];   // je-jb >= 1 (self-loop)
    const int jlast = je - 1;
    auto LD = [&](int j) -> uint4 {
        int jj = (j < jlast) ? j : jlast;       // clamp: re-reads hot line only
        return *(const uint4*)(xl + (size_t)srcList[jj] * 512 + lane * 8);
    };
    uint4 q0 = LD(jb), q1 = LD(jb + 1), q2 = LD(jb + 2);
    for (int j = jb; j < je; ++j) {
        uint4 cur = q0; q0 = q1; q1 = q2; q2 = LD(j + 3);

        float b[8];
        b[0]=bf_lo(cur.x); b[1]=bf_hi(cur.x); b[2]=bf_lo(cur.y); b[3]=bf_hi(cur.y);
        b[4]=bf_lo(cur.z); b[5]=bf_hi(cur.z); b[6]=bf_lo(cur.w); b[7]=bf_hi(cur.w);
        float p = 0.f;
        #pragma unroll
        for (int k = 0; k < 8; ++k) {
            float s  = b[k] + r[k];
            float lr2 = fmaxf(s, 0.f) + NEG_SLOPE * fminf(s, 0.f);
            p = fmaf(lr2, at[k], p);
        }
        p += __shfl_xor(p, 1, 64);
        p += __shfl_xor(p, 2, 64);
        p += __shfl_xor(p, 4, 64);
        p += __shfl_xor(p, 8, 64);
        float w = __expf(p);
        lh += w;
        #pragma unroll
        for (int k = 0; k < 8; ++k) acc[k] = fmaf(w, b[k], acc[k]);
    }

    const float inv = 1.0f / lh;
    const int d0 = (lane & 15) * 8;
    const size_t xo = (size_t)v * 128 + d0;

    float4 xv0 = *(const float4*)(x + xo);
    float4 xv1 = *(const float4*)(x + xo + 4);
    float4 bb0 = *(const float4*)(bias + d0);
    float4 bb1 = *(const float4*)(bias + d0 + 4);
    float xr8[8] = {xv0.x,xv0.y,xv0.z,xv0.w,xv1.x,xv1.y,xv1.z,xv1.w};
    float bi8[8] = {bb0.x,bb0.y,bb0.z,bb0.w,bb1.x,bb1.y,bb1.z,bb1.w};

    float y[8];
    float s = 0.f;
    #pragma unroll
    for (int k = 0; k < 8; ++k) {
        float o = acc[k] * inv;
        o += __shfl_xor(o, 16, 64);
        o += __shfl_xor(o, 32, 64);
        float yy = xr8[k] + o * 0.25f + bi8[k];
        y[k] = yy;
        s += yy;
    }
    s += __shfl_xor(s, 1, 64);
    s += __shfl_xor(s, 2, 64);
    s += __shfl_xor(s, 4, 64);
    s += __shfl_xor(s, 8, 64);
    float mu = s * (1.0f / 128.0f);
    float ss = 0.f;
    #pragma unroll
    for (int k = 0; k < 8; ++k) { float d = y[k] - mu; ss += d * d; }
    ss += __shfl_xor(ss, 1, 64);
    ss += __shfl_xor(ss, 2, 64);
    ss += __shfl_xor(ss, 4, 64);
    ss += __shfl_xor(ss, 8, 64);
    float rs = rsqrtf(ss * (1.0f / 128.0f) + LN_EPS);

    if ((lane >> 4) == 0) {                   // quarters hold identical y
        float4 g0 = *(const float4*)(g1 + d0);
        float4 g4 = *(const float4*)(g1 + d0 + 4);
        float4 e0 = *(const float4*)(be1 + d0);
        float4 e4 = *(const float4*)(be1 + d0 + 4);
        float gg[8] = {g0.x,g0.y,g0.z,g0.w,g4.x,g4.y,g4.z,g4.w};
        float ee[8] = {e0.x,e0.y,e0.z,e0.w,e4.x,e4.y,e4.z,e4.w};
        float z[8];
        #pragma unroll
        for (int k = 0; k < 8; ++k) z[k] = (y[k] - mu) * rs * gg[k] + ee[k];
        ushort4 zb0, zb1;
        zb0.x=f2bf(z[0]); zb0.y=f2bf(z[1]); zb0.z=f2bf(z[2]); zb0.w=f2bf(z[3]);
        zb1.x=f2bf(z[4]); zb1.y=f2bf(z[5]); zb1.z=f2bf(z[6]); zb1.w=f2bf(z[7]);
        *(ushort4*)(x1b + xo)     = zb0;
        *(ushort4*)(x1b + xo + 4) = zb1;
    }
}

// ---------------------------------------------------------------------------
// Fused FFN: h = GELU(x1b@W1^T+b1); f = h@W2^T+b2; out = LN2(x1b + f).
// Residual read from the staged As tile (no global re-read).
// ---------------------------------------------------------------------------
__global__ __launch_bounds__(256) void ffn_fused(
    const ushort* __restrict__ x1b, const ushort* __restrict__ w1b,
    const float* __restrict__ b1, const ushort* __restrict__ w2b,
    const float* __restrict__ b2, const float* __restrict__ g2,
    const float* __restrict__ be2, float* __restrict__ out)
{
    __shared__ ushort As[128 * 128];   // x1b tile       32 KB
    __shared__ ushort Bs[128 * 128];   // weight tile    32 KB
    __shared__ ushort Ts[128 * 128];   // hidden half / stats  32 KB
    const int tid  = threadIdx.x;
    const int rb   = blockIdx.x * 128;
    const int wave = tid >> 6, lane = tid & 63;
    const int wm   = (wave >> 1) * 64, wn = (wave & 1) * 64;
    const int lr   = lane & 15, lq = lane >> 4;

    #pragma unroll
    for (int i = 0; i < 8; ++i) {
        int chunk = tid + i * 256;
        int rr = chunk >> 4, cc = chunk & 15;
        int gr = rb + rr;
        uint4 va = make_uint4(0u,0u,0u,0u);
        if (gr < N_NODES) va = *(const uint4*)(x1b + (size_t)gr * 128 + cc * 8);
        *(uint4*)(As + rr * 128 + ((cc ^ (rr & 15)) * 8)) = va;
    }

    f32x4 zero = {0.f,0.f,0.f,0.f};
    f32x4 acc2[4][4];
    #pragma unroll
    for (int i = 0; i < 4; ++i)
        #pragma unroll
        for (int j = 0; j < 4; ++j) acc2[i][j] = zero;

    for (int half = 0; half < 2; ++half) {
        __syncthreads();
        #pragma unroll
        for (int i = 0; i < 8; ++i) {
            int chunk = tid + i * 256;
            int rr = chunk >> 4, cc = chunk & 15;
            uint4 vb = *(const uint4*)(w1b + (size_t)(half * 128 + rr) * 128 + cc * 8);
            *(uint4*)(Bs + rr * 128 + ((cc ^ (rr & 15)) * 8)) = vb;
        }
        __syncthreads();

        f32x4 acc1[4][4];
        #pragma unroll
        for (int i = 0; i < 4; ++i)
            #pragma unroll
            for (int j = 0; j < 4; ++j) acc1[i][j] = zero;

        #pragma unroll
        for (int q = 0; q < 4; ++q) {
            int csw = ((q * 4 + lq) ^ lr) * 8;
            bf16x8 bfr[4], af[4];
            #pragma unroll
            for (int i = 0; i < 4; ++i) {
                bfr[i] = *(const bf16x8*)(Bs + (wm + i * 16 + lr) * 128 + csw);
                af[i]  = *(const bf16x8*)(As + (wn + i * 16 + lr) * 128 + csw);
            }
            #pragma unroll
            for (int i = 0; i < 4; ++i)
                #pragma unroll
                for (int j = 0; j < 4; ++j)
                    acc1[i][j] = __builtin_amdgcn_mfma_f32_16x16x32_bf16(
                        bfr[i], af[j], acc1[i][j], 0, 0, 0);
        }

        #pragma unroll
        for (int i = 0; i < 4; ++i) {
            int wc = wm + i * 16 + lq * 4;
            float4 bv = *(const float4*)(b1 + half * 128 + wc);
            #pragma unroll
            for (int j = 0; j < 4; ++j) {
                int nl = wn + j * 16 + lr;
                float v0 = acc1[i][j][0] + bv.x;
                float v1 = acc1[i][j][1] + bv.y;
                float v2 = acc1[i][j][2] + bv.z;
                float v3 = acc1[i][j][3] + bv.w;
                v0 = v0 * 0.5f * (1.0f + erff(v0 * 0.70710678118654752f));
                v1 = v1 * 0.5f * (1.0f + erff(v1 * 0.70710678118654752f));
                v2 = v2 * 0.5f * (1.0f + erff(v2 * 0.70710678118654752f));
                v3 = v3 * 0.5f * (1.0f + erff(v3 * 0.70710678118654752f));
                ushort4 o;
                o.x = f2bf(v0); o.y = f2bf(v1); o.z = f2bf(v2); o.w = f2bf(v3);
                int sw = (((wc >> 3) ^ (nl & 15)) * 8) + (wc & 7);
                *(ushort4*)(Ts + nl * 128 + sw) = o;
            }
        }
        __syncthreads();
        #pragma unroll
        for (int i = 0; i < 8; ++i) {
            int chunk = tid + i * 256;
            int rr = chunk >> 4, cc = chunk & 15;
            uint4 vb = *(const uint4*)(w2b + (size_t)rr * 256 + half * 128 + cc * 8);
            *(uint4*)(Bs + rr * 128 + ((cc ^ (rr & 15)) * 8)) = vb;
        }
        __syncthreads();

        #pragma unroll
        for (int q = 0; q < 4; ++q) {
            int csw = ((q * 4 + lq) ^ lr) * 8;
            bf16x8 bfr[4], af[4];
            #pragma unroll
            for (int i = 0; i < 4; ++i) {
                bfr[i] = *(const bf16x8*)(Bs + (wm + i * 16 + lr) * 128 + csw);
                af[i]  = *(const bf16x8*)(Ts + (wn + i * 16 + lr) * 128 + csw);
            }
            #pragma unroll
            for (int i = 0; i < 4; ++i)
                #pragma unroll
                for (int j = 0; j < 4; ++j)
                    acc2[i][j] = __builtin_amdgcn_mfma_f32_16x16x32_bf16(
                        bfr[i], af[j], acc2[i][j], 0, 0, 0);
        }
    }

    __syncthreads();                          // Ts now reusable for stats
    float* sums = (float*)Ts;                 // [2][128]
    float* ssqs = (float*)(Ts + 2048);        // [2][128]

    #pragma unroll
    for (int j = 0; j < 4; ++j) {
        int nl = wn + j * 16 + lr;
        float s = 0.f, q2 = 0.f;
        #pragma unroll
        for (int i = 0; i < 4; ++i) {
            int wc = wm + i * 16 + lq * 4;
            float4 bv = *(const float4*)(b2 + wc);
            // residual from staged As tile (swizzled; 4 ushorts within one chunk)
            const ushort* ap = As + nl * 128 + (((wc >> 3) ^ (nl & 15)) * 8) + (wc & 7);
            float y0 = acc2[i][j][0] + bv.x + bfu(ap[0]);
            float y1 = acc2[i][j][1] + bv.y + bfu(ap[1]);
            float y2 = acc2[i][j][2] + bv.z + bfu(ap[2]);
            float y3 = acc2[i][j][3] + bv.w + bfu(ap[3]);
            acc2[i][j][0] = y0; acc2[i][j][1] = y1;
            acc2[i][j][2] = y2; acc2[i][j][3] = y3;
            s  += y0 + y1 + y2 + y3;
            q2 += y0*y0 + y1*y1 + y2*y2 + y3*y3;
        }
        s  += __shfl_xor(s, 16, 64);  s  += __shfl_xor(s, 32, 64);
        q2 += __shfl_xor(q2, 16, 64); q2 += __shfl_xor(q2, 32, 64);
        if (lq == 0) {
            int half = wm >> 6;
            sums[half * 128 + nl] = s;
            ssqs[half * 128 + nl] = q2;
        }
    }
    __syncthreads();

    #pragma unroll
    for (int j = 0; j < 4; ++j) {
        int nl = wn + j * 16 + lr;
        int node = rb + nl;
        if (node >= N_NODES) continue;
        float tot = sums[nl] + sums[128 + nl];
        float tq  = ssqs[nl] + ssqs[128 + nl];
        float mu  = tot * (1.0f / 128.0f);
        float var = tq * (1.0f / 128.0f) - mu * mu;
        float rs  = rsqrtf(var + LN_EPS);
        #pragma unroll
        for (int i = 0; i < 4; ++i) {
            int wc = wm + i * 16 + lq * 4;
            float4 gv = *(const float4*)(g2 + wc);
            float4 ev = *(const float4*)(be2 + wc);
            float4 o;
            o.x = (acc2[i][j][0] - mu) * rs * gv.x + ev.x;
            o.y = (acc2[i][j][1] - mu) * rs * gv.y + ev.y;
            o.z = (acc2[i][j][2] - mu) * rs * gv.z + ev.z;
            o.w = (acc2[i][j][3] - mu) * rs * gv.w + ev.w;
            *(float4*)(out + (size_t)node * 128 + wc) = o;
        }
    }
}

// ---------------------------------------------------------------------------
extern "C" void kernel_launch(void* const* d_in, const int* in_sizes, int n_in,
                              void* d_out, int out_size, void* d_ws, size_t ws_size,
                              hipStream_t stream)
{
    const float* x    = (const float*)d_in[0];
    const int*   ei   = (const int*)  d_in[1];
    const float* Wl   = (const float*)d_in[2];
    const float* bl   = (const float*)d_in[3];
    const float* Wr   = (const float*)d_in[4];
    const float* br   = (const float*)d_in[5];
    const float* att  = (const float*)d_in[6];
    const float* bias = (const float*)d_in[7];
    const float* g1   = (const float*)d_in[8];
    const float* be1  = (const float*)d_in[9];
    const float* W1   = (const float*)d_in[10];
    const float* b1   = (const float*)d_in[11];
    const float* W2   = (const float*)d_in[12];
    const float* b2   = (const float*)d_in[13];
    const float* g2   = (const float*)d_in[14];
    const float* be2  = (const float*)d_in[15];
    float* out = (float*)d_out;

    char* ws = (char*)d_ws;
    size_t off = 0;
    auto alloc = [&](size_t bytes) -> void* {
        void* p = ws + off;
        off = (off + bytes + 255) & ~(size_t)255;
        return p;
    };
    ushort* xlb  = (ushort*)alloc((size_t)N_NODES * 512 * 2);
    ushort* xrb  = (ushort*)alloc((size_t)N_NODES * 512 * 2);
    ushort* x1b  = (ushort*)alloc((size_t)N_NODES * 128 * 2);
    ushort* wb   = (ushort*)alloc((size_t)197120 * 2);
    int*   offs    = (int*)alloc((size_t)(N_NODES + 1) * 4);
    int*   counts  = (int*)alloc((size_t)N_NODES * 4 * 2);  // counts + cursor
    int*   cursor  = counts + N_NODES;
    unsigned long long* state = (unsigned long long*)alloc(256 * 4);
    int*   srcList = (int*)alloc((size_t)EN_TOT * 4);

    ushort* wcat = wb;              // [Wl;Wr] 1024x128
    ushort* w1b  = wb + 131072;
    ushort* w2b  = wb + 163840;
    ushort* attb = wb + 196608;

    prep<<<770, 256, 0, stream>>>(Wl, Wr, W1, W2, att, wb, counts, (int*)state);

    gemm_lr<<<391, 256, 0, stream>>>(x, wcat, bl, br, xlb, xrb,
                                     ei + N_EDGES, counts);

    scan_lb<<<NC_SCAN, 64, 0, stream>>>(counts, offs, state);
    scatter_edges<<<(EN_TOT + 255) / 256, 256, 0, stream>>>(ei, ei + N_EDGES,
                                                           offs, cursor, srcList);

    gat_fused<<<12500, 256, 0, stream>>>(x, xlb, xrb, offs, srcList, attb,
                                         bias, g1, be1, x1b);

    ffn_fused<<<391, 256, 0, stream>>>(x1b, w1b, b1, w2b, b2, g2, be2, out);
}

// Round 9
// 301.958 us; speedup vs baseline: 1.3806x; 1.0060x over previous
//
#include <hip/hip_runtime.h>
#include <cstdint>
#include <cstddef>

#define N_NODES 50000
#define N_EDGES 400000
#define EN_TOT  (N_EDGES + N_NODES)
#define NC_SCAN ((N_NODES + 511) / 512)   // 98
#define LN_EPS 1e-5f

typedef _Float16 h2    __attribute__((ext_vector_type(2)));
typedef __fp16   g2t   __attribute__((ext_vector_type(2)));   // builtin ABI type
typedef _Float16 f16x8 __attribute__((ext_vector_type(8)));
typedef float    f32x4 __attribute__((ext_vector_type(4)));

__device__ __forceinline__ uint32_t pkh(float a, float b) {
    g2t t = __builtin_amdgcn_cvt_pkrtz(a, b);
    union { g2t h; uint32_t u; } c; c.h = t; return c.u;
}
__device__ __forceinline__ h2 as_h2(uint32_t u) {
    union { uint32_t u; h2 h; } c; c.u = u; return c.h;
}
__device__ __forceinline__ float fdot2(h2 a, h2 b, float c) {
    union { h2 h; g2t g; } ca, cb; ca.h = a; cb.h = b;
    return __builtin_amdgcn_fdot2(ca.g, cb.g, c, false);
}
__device__ __forceinline__ float hfu(ushort v) {
    union { ushort u; _Float16 h; } c; c.u = v; return (float)c.h;
}

// ---------------------------------------------------------------------------
// prep: weights -> fp16 AND zero counts/cursor/scan-state.
// wb: [Wl 65536 | Wr 65536 | W1 32768 | W2 32768 | att 512]
// ---------------------------------------------------------------------------
__global__ __launch_bounds__(256) void prep(
    const float* __restrict__ Wl, const float* __restrict__ Wr,
    const float* __restrict__ W1, const float* __restrict__ W2,
    const float* __restrict__ att, ushort* __restrict__ wb,
    int* __restrict__ counts2 /*100000 ints*/, int* __restrict__ state /*256 ints*/)
{
    int i = blockIdx.x * 256 + threadIdx.x;          // 770*256 == 197120 exact
    const float* src; int off;
    if (i < 65536)       { src = Wl;  off = i; }
    else if (i < 131072) { src = Wr;  off = i - 65536; }
    else if (i < 163840) { src = W1;  off = i - 131072; }
    else if (i < 196608) { src = W2;  off = i - 163840; }
    else                 { src = att; off = i - 196608; }
    union { _Float16 h; ushort u; } c; c.h = (_Float16)src[off];
    wb[i] = c.u;
    if (i < 100000) counts2[i] = 0;
    if (i < 256)    state[i] = 0;
}

// ---------------------------------------------------------------------------
// xl/xr GEMM, A-stationary over 8 col-tiles of Wcat=[Wl;Wr], fp16 MFMA.
// + folded-in degree counting. Output restaged through LDS -> coalesced.
// ---------------------------------------------------------------------------
__global__ __launch_bounds__(256) void gemm_lr(
    const float* __restrict__ x, const ushort* __restrict__ wcat,
    const float* __restrict__ bl, const float* __restrict__ br,
    ushort* __restrict__ xlb, ushort* __restrict__ xrb,
    const int* __restrict__ dst, int* __restrict__ counts)
{
    __shared__ ushort As[128 * 128];   // 32 KB
    __shared__ ushort Bs[128 * 136];   // weights stride 128; out restage stride 136
    const int tid  = threadIdx.x;
    const int rb   = blockIdx.x * 128;
    const int wave = tid >> 6, lane = tid & 63;
    const int wm   = (wave >> 1) * 64, wn = (wave & 1) * 64;
    const int lr   = lane & 15, lq = lane >> 4;

    {   // folded count_deg: this block's slice of edges (391*1152 >= EN_TOT)
        int e0 = blockIdx.x * 1152;
        int e1 = e0 + 1152; if (e1 > EN_TOT) e1 = EN_TOT;
        for (int e = e0 + tid; e < e1; e += 256) {
            int d = (e < N_EDGES) ? dst[e] : (e - N_EDGES);
            atomicAdd(counts + d, 1);
        }
    }

    #pragma unroll
    for (int i = 0; i < 8; ++i) {
        int chunk = tid + i * 256;          // 0..2047
        int rr = chunk >> 4, cc = chunk & 15;
        int gr = rb + rr;
        float4 v0 = make_float4(0.f,0.f,0.f,0.f), v1 = v0;
        if (gr < N_NODES) {
            v0 = *(const float4*)(x + (size_t)gr * 128 + cc * 8);
            v1 = *(const float4*)(x + (size_t)gr * 128 + cc * 8 + 4);
        }
        uint4 h = make_uint4(pkh(v0.x,v0.y), pkh(v0.z,v0.w),
                             pkh(v1.x,v1.y), pkh(v1.z,v1.w));
        *(uint4*)(As + rr * 128 + ((cc ^ (rr & 15)) * 8)) = h;
    }

    for (int cbk = 0; cbk < 8; ++cbk) {
        __syncthreads();
        #pragma unroll
        for (int i = 0; i < 8; ++i) {
            int chunk = tid + i * 256;
            int rr = chunk >> 4, cc = chunk & 15;
            uint4 vb = *(const uint4*)(wcat + (size_t)(cbk * 128 + rr) * 128 + cc * 8);
            *(uint4*)(Bs + rr * 128 + ((cc ^ (rr & 15)) * 8)) = vb;
        }
        __syncthreads();

        f32x4 zero = {0.f,0.f,0.f,0.f};
        f32x4 acc[4][4];
        #pragma unroll
        for (int i = 0; i < 4; ++i)
            #pragma unroll
            for (int j = 0; j < 4; ++j) acc[i][j] = zero;

        #pragma unroll
        for (int q = 0; q < 4; ++q) {
            int csw = ((q * 4 + lq) ^ lr) * 8;
            f16x8 bfr[4], af[4];
            #pragma unroll
            for (int i = 0; i < 4; ++i) {
                bfr[i] = *(const f16x8*)(Bs + (wm + i * 16 + lr) * 128 + csw);
                af[i]  = *(const f16x8*)(As + (wn + i * 16 + lr) * 128 + csw);
            }
            #pragma unroll
            for (int i = 0; i < 4; ++i)
                #pragma unroll
                for (int j = 0; j < 4; ++j)
                    acc[i][j] = __builtin_amdgcn_mfma_f32_16x16x32_f16(
                        bfr[i], af[j], acc[i][j], 0, 0, 0);
        }

        __syncthreads();                 // MFMA reads of Bs done -> restage output
        const float* bias = (cbk < 4) ? bl : br;
        ushort* outp = (cbk < 4) ? xlb : xrb;
        const int cloc = (cbk & 3) * 128;
        #pragma unroll
        for (int i = 0; i < 4; ++i) {
            int wc = wm + i * 16 + lq * 4;
            float4 bv = *(const float4*)(bias + cloc + wc);
            #pragma unroll
            for (int j = 0; j < 4; ++j) {
                int nl = wn + j * 16 + lr;
                uint2 o;
                o.x = pkh(acc[i][j][0] + bv.x, acc[i][j][1] + bv.y);
                o.y = pkh(acc[i][j][2] + bv.z, acc[i][j][3] + bv.w);
                *(uint2*)(Bs + nl * 136 + wc) = o;
            }
        }
        __syncthreads();
        #pragma unroll
        for (int i = 0; i < 8; ++i) {
            int chunk = tid + i * 256;     // 0..2047
            int row = chunk >> 4, cc = chunk & 15;
            int node = rb + row;
            if (node < N_NODES) {
                uint4 v = *(const uint4*)(Bs + row * 136 + cc * 8);
                *(uint4*)(outp + (size_t)node * 512 + cloc + cc * 8) = v;
            }
        }
    }
}

// ---------------------------------------------------------------------------
// CSR: single-dispatch decoupled-lookback scan -> scatter
// ---------------------------------------------------------------------------
__global__ __launch_bounds__(64) void scan_lb(const int* __restrict__ counts,
                                              int* __restrict__ offs,
                                              unsigned long long* __restrict__ state)
{
    const int b = blockIdx.x, lane = threadIdx.x;
    const int base = b * 512 + lane * 8;
    int cnt[8];
    int s = 0;
    #pragma unroll
    for (int k = 0; k < 8; ++k) {
        int idx = base + k;
        cnt[k] = (idx < N_NODES) ? counts[idx] : 0;
        s += cnt[k];
    }
    int inc = s;
    #pragma unroll
    for (int d = 1; d < 64; d <<= 1) {
        int t = __shfl_up(inc, d, 64);
        if (lane >= d) inc += t;
    }
    const int total = __shfl(inc, 63, 64);

    if (lane == 0) {
        unsigned long long pub = ((unsigned long long)(b == 0 ? 2u : 1u) << 32)
                               | (unsigned)total;
        atomicExch(&state[b], pub);
    }

    int prefix = 0;
    if (b > 0) {
        int p0 = b - 1;
        while (true) {
            int p = p0 - lane;
            int flag, val;
            if (p >= 0) {
                unsigned long long v;
                do { v = atomicAdd(&state[p], 0ULL); flag = (int)(v >> 32); }
                while (flag == 0);
                val = (int)(unsigned)v;
            } else { flag = 2; val = 0; }
            unsigned long long mask = __ballot(flag == 2);
            int L = mask ? (__ffsll(mask) - 1) : 64;
            int take = (lane <= L) ? val : 0;
            #pragma unroll
            for (int m = 32; m; m >>= 1) take += __shfl_xor(take, m, 64);
            prefix += take;
            if (L < 64) break;
            p0 -= 64;
        }
        if (lane == 0)
            atomicExch(&state[b], (2ULL << 32) | (unsigned)(prefix + total));
    }

    int run = prefix + inc - s;
    #pragma unroll
    for (int k = 0; k < 8; ++k) {
        int idx = base + k;
        if (idx < N_NODES) { offs[idx] = run; run += cnt[k]; }
    }
    if (b == NC_SCAN - 1 && lane == 63) offs[N_NODES] = prefix + inc;
}

__global__ __launch_bounds__(256) void scatter_edges(
    const int* __restrict__ src, const int* __restrict__ dst,
    const int* __restrict__ offs, int* __restrict__ cursor,
    int* __restrict__ srcList)
{
    int i = blockIdx.x * 256 + threadIdx.x;
    if (i >= EN_TOT) return;
    int s, d;
    if (i < N_EDGES) { s = src[i]; d = dst[i]; }
    else             { s = d = i - N_EDGES; }
    int pos = atomicAdd(cursor + d, 1);
    srcList[offs[d] + pos] = s;
}

// ---------------------------------------------------------------------------
// GATv2 per destination node (one wave each), fp16 packed-math inner loop:
// pk add/mul/max leakyrelu, v_dot2_f32_f16 logits, pk_fma accumulation;
// srcList index scalarized via readfirstlane.
// + head-mean + bias + residual + LN1 -> x1b (fp16)
// ---------------------------------------------------------------------------
__global__ __launch_bounds__(256) void gat_fused(
    const float* __restrict__ x, const ushort* __restrict__ xl,
    const ushort* __restrict__ xr, const int* __restrict__ offs,
    const int* __restrict__ srcList, const ushort* __restrict__ attb,
    const float* __restrict__ bias, const float* __restrict__ g1,
    const float* __restrict__ be1, ushort* __restrict__ x1b)
{
    const int wave = threadIdx.x >> 6;
    const int lane = threadIdx.x & 63;
    const int v = blockIdx.x * 4 + wave;
    if (v >= N_NODES) return;

    uint4 rw = *(const uint4*)(xr + (size_t)v * 512 + lane * 8);
    uint4 aw = *(const uint4*)(attb + lane * 8);
    h2 r0 = as_h2(rw.x), r1 = as_h2(rw.y), r2 = as_h2(rw.z), r3 = as_h2(rw.w);
    h2 a0 = as_h2(aw.x), a1 = as_h2(aw.y), a2 = as_h2(aw.z), a3 = as_h2(aw.w);
    const h2 k02 = {(_Float16)0.2f, (_Float16)0.2f};

    h2 acc0 = {0, 0}, acc1 = {0, 0}, acc2 = {0, 0}, acc3 = {0, 0};
    float lh = 0.f;

    const int jb = offs[v], je = offs[v + 1];   // >= 1 edge (self-loop)
    int u = __builtin_amdgcn_readfirstlane(srcList[jb]);
    uint4 cur = *(const uint4*)(xl + (size_t)u * 512 + lane * 8);
    for (int j = jb; j < je; ++j) {
        int jn = (j + 1 < je) ? (j + 1) : j;
        int un = __builtin_amdgcn_readfirstlane(srcList[jn]);
        uint4 nxt = *(const uint4*)(xl + (size_t)un * 512 + lane * 8);

        h2 b0 = as_h2(cur.x), b1 = as_h2(cur.y), b2 = as_h2(cur.z), b3 = as_h2(cur.w);
        h2 s0 = b0 + r0, s1 = b1 + r1, s2 = b2 + r2, s3 = b3 + r3;
        h2 l0 = __builtin_elementwise_max(s0, s0 * k02);
        h2 l1 = __builtin_elementwise_max(s1, s1 * k02);
        h2 l2 = __builtin_elementwise_max(s2, s2 * k02);
        h2 l3 = __builtin_elementwise_max(s3, s3 * k02);
        float p = 0.f;
        p = fdot2(l0, a0, p);
        p = fdot2(l1, a1, p);
        p = fdot2(l2, a2, p);
        p = fdot2(l3, a3, p);
        p += __shfl_xor(p, 1, 64);
        p += __shfl_xor(p, 2, 64);
        p += __shfl_xor(p, 4, 64);
        p += __shfl_xor(p, 8, 64);
        float w = __expf(p);
        lh += w;
        h2 wh = as_h2(pkh(w, w));
        acc0 += wh * b0;
        acc1 += wh * b1;
        acc2 += wh * b2;
        acc3 += wh * b3;
        cur = nxt;
    }

    const float inv = 1.0f / lh;
    float o8[8] = {(float)acc0[0], (float)acc0[1], (float)acc1[0], (float)acc1[1],
                   (float)acc2[0], (float)acc2[1], (float)acc3[0], (float)acc3[1]};

    const int d0 = (lane & 15) * 8;
    const size_t xo = (size_t)v * 128 + d0;

    float4 xv0 = *(const float4*)(x + xo);
    float4 xv1 = *(const float4*)(x + xo + 4);
    float4 bb0 = *(const float4*)(bias + d0);
    float4 bb1 = *(const float4*)(bias + d0 + 4);
    float xr8[8] = {xv0.x,xv0.y,xv0.z,xv0.w,xv1.x,xv1.y,xv1.z,xv1.w};
    float bi8[8] = {bb0.x,bb0.y,bb0.z,bb0.w,bb1.x,bb1.y,bb1.z,bb1.w};

    float y[8];
    float s = 0.f;
    #pragma unroll
    for (int k = 0; k < 8; ++k) {
        float o = o8[k] * inv;
        o += __shfl_xor(o, 16, 64);             // sum across heads
        o += __shfl_xor(o, 32, 64);
        float yy = xr8[k] + o * 0.25f + bi8[k]; // head mean + bias + residual
        y[k] = yy;
        s += yy;
    }
    s += __shfl_xor(s, 1, 64);
    s += __shfl_xor(s, 2, 64);
    s += __shfl_xor(s, 4, 64);
    s += __shfl_xor(s, 8, 64);
    float mu = s * (1.0f / 128.0f);
    float ss = 0.f;
    #pragma unroll
    for (int k = 0; k < 8; ++k) { float d = y[k] - mu; ss += d * d; }
    ss += __shfl_xor(ss, 1, 64);
    ss += __shfl_xor(ss, 2, 64);
    ss += __shfl_xor(ss, 4, 64);
    ss += __shfl_xor(ss, 8, 64);
    float rs = rsqrtf(ss * (1.0f / 128.0f) + LN_EPS);

    if ((lane >> 4) == 0) {                   // quarters hold identical y
        float4 g0 = *(const float4*)(g1 + d0);
        float4 g4 = *(const float4*)(g1 + d0 + 4);
        float4 e0 = *(const float4*)(be1 + d0);
        float4 e4 = *(const float4*)(be1 + d0 + 4);
        float gg[8] = {g0.x,g0.y,g0.z,g0.w,g4.x,g4.y,g4.z,g4.w};
        float ee[8] = {e0.x,e0.y,e0.z,e0.w,e4.x,e4.y,e4.z,e4.w};
        float z[8];
        #pragma unroll
        for (int k = 0; k < 8; ++k) z[k] = (y[k] - mu) * rs * gg[k] + ee[k];
        uint2 z0, z1;
        z0.x = pkh(z[0], z[1]); z0.y = pkh(z[2], z[3]);
        z1.x = pkh(z[4], z[5]); z1.y = pkh(z[6], z[7]);
        *(uint2*)(x1b + xo)     = z0;
        *(uint2*)(x1b + xo + 4) = z1;
    }
}

// ---------------------------------------------------------------------------
// Fused FFN (fp16): h = GELU(x1b@W1^T+b1); f = h@W2^T+b2; out = LN2(x1b+f).
// Residual read from the staged As tile.
// ---------------------------------------------------------------------------
__global__ __launch_bounds__(256) void ffn_fused(
    const ushort* __restrict__ x1b, const ushort* __restrict__ w1b,
    const float* __restrict__ b1, const ushort* __restrict__ w2b,
    const float* __restrict__ b2, const float* __restrict__ g2,
    const float* __restrict__ be2, float* __restrict__ out)
{
    __shared__ ushort As[128 * 128];   // x1b tile       32 KB
    __shared__ ushort Bs[128 * 128];   // weight tile    32 KB
    __shared__ ushort Ts[128 * 128];   // hidden half / stats  32 KB
    const int tid  = threadIdx.x;
    const int rb   = blockIdx.x * 128;
    const int wave = tid >> 6, lane = tid & 63;
    const int wm   = (wave >> 1) * 64, wn = (wave & 1) * 64;
    const int lr   = lane & 15, lq = lane >> 4;

    #pragma unroll
    for (int i = 0; i < 8; ++i) {
        int chunk = tid + i * 256;
        int rr = chunk >> 4, cc = chunk & 15;
        int gr = rb + rr;
        uint4 va = make_uint4(0u,0u,0u,0u);
        if (gr < N_NODES) va = *(const uint4*)(x1b + (size_t)gr * 128 + cc * 8);
        *(uint4*)(As + rr * 128 + ((cc ^ (rr & 15)) * 8)) = va;
    }

    f32x4 zero = {0.f,0.f,0.f,0.f};
    f32x4 acc2[4][4];
    #pragma unroll
    for (int i = 0; i < 4; ++i)
        #pragma unroll
        for (int j = 0; j < 4; ++j) acc2[i][j] = zero;

    for (int half = 0; half < 2; ++half) {
        __syncthreads();
        #pragma unroll
        for (int i = 0; i < 8; ++i) {
            int chunk = tid + i * 256;
            int rr = chunk >> 4, cc = chunk & 15;
            uint4 vb = *(const uint4*)(w1b + (size_t)(half * 128 + rr) * 128 + cc * 8);
            *(uint4*)(Bs + rr * 128 + ((cc ^ (rr & 15)) * 8)) = vb;
        }
        __syncthreads();

        f32x4 acc1[4][4];
        #pragma unroll
        for (int i = 0; i < 4; ++i)
            #pragma unroll
            for (int j = 0; j < 4; ++j) acc1[i][j] = zero;

        #pragma unroll
        for (int q = 0; q < 4; ++q) {
            int csw = ((q * 4 + lq) ^ lr) * 8;
            f16x8 bfr[4], af[4];
            #pragma unroll
            for (int i = 0; i < 4; ++i) {
                bfr[i] = *(const f16x8*)(Bs + (wm + i * 16 + lr) * 128 + csw);
                af[i]  = *(const f16x8*)(As + (wn + i * 16 + lr) * 128 + csw);
            }
            #pragma unroll
            for (int i = 0; i < 4; ++i)
                #pragma unroll
                for (int j = 0; j < 4; ++j)
                    acc1[i][j] = __builtin_amdgcn_mfma_f32_16x16x32_f16(
                        bfr[i], af[j], acc1[i][j], 0, 0, 0);
        }

        #pragma unroll
        for (int i = 0; i < 4; ++i) {
            int wc = wm + i * 16 + lq * 4;
            float4 bv = *(const float4*)(b1 + half * 128 + wc);
            #pragma unroll
            for (int j = 0; j < 4; ++j) {
                int nl = wn + j * 16 + lr;
                float v0 = acc1[i][j][0] + bv.x;
                float v1 = acc1[i][j][1] + bv.y;
                float v2 = acc1[i][j][2] + bv.z;
                float v3 = acc1[i][j][3] + bv.w;
                v0 = v0 * 0.5f * (1.0f + erff(v0 * 0.70710678118654752f));
                v1 = v1 * 0.5f * (1.0f + erff(v1 * 0.70710678118654752f));
                v2 = v2 * 0.5f * (1.0f + erff(v2 * 0.70710678118654752f));
                v3 = v3 * 0.5f * (1.0f + erff(v3 * 0.70710678118654752f));
                uint2 o;
                o.x = pkh(v0, v1); o.y = pkh(v2, v3);
                int sw = (((wc >> 3) ^ (nl & 15)) * 8) + (wc & 7);
                *(uint2*)(Ts + nl * 128 + sw) = o;
            }
        }
        __syncthreads();
        #pragma unroll
        for (int i = 0; i < 8; ++i) {
            int chunk = tid + i * 256;
            int rr = chunk >> 4, cc = chunk & 15;
            uint4 vb = *(const uint4*)(w2b + (size_t)rr * 256 + half * 128 + cc * 8);
            *(uint4*)(Bs + rr * 128 + ((cc ^ (rr & 15)) * 8)) = vb;
        }
        __syncthreads();

        #pragma unroll
        for (int q = 0; q < 4; ++q) {
            int csw = ((q * 4 + lq) ^ lr) * 8;
            f16x8 bfr[4], af[4];
            #pragma unroll
            for (int i = 0; i < 4; ++i) {
                bfr[i] = *(const f16x8*)(Bs + (wm + i * 16 + lr) * 128 + csw);
                af[i]  = *(const f16x8*)(Ts + (wn + i * 16 + lr) * 128 + csw);
            }
            #pragma unroll
            for (int i = 0; i < 4; ++i)
                #pragma unroll
                for (int j = 0; j < 4; ++j)
                    acc2[i][j] = __builtin_amdgcn_mfma_f32_16x16x32_f16(
                        bfr[i], af[j], acc2[i][j], 0, 0, 0);
        }
    }

    __syncthreads();                          // Ts reusable for stats
    float* sums = (float*)Ts;                 // [2][128]
    float* ssqs = (float*)(Ts + 2048);        // [2][128]

    #pragma unroll
    for (int j = 0; j < 4; ++j) {
        int nl = wn + j * 16 + lr;
        float s = 0.f, q2 = 0.f;
        #pragma unroll
        for (int i = 0; i < 4; ++i) {
            int wc = wm + i * 16 + lq * 4;
            float4 bv = *(const float4*)(b2 + wc);
            const ushort* ap = As + nl * 128 + (((wc >> 3) ^ (nl & 15)) * 8) + (wc & 7);
            float y0 = acc2[i][j][0] + bv.x + hfu(ap[0]);
            float y1 = acc2[i][j][1] + bv.y + hfu(ap[1]);
            float y2 = acc2[i][j][2] + bv.z + hfu(ap[2]);
            float y3 = acc2[i][j][3] + bv.w + hfu(ap[3]);
            acc2[i][j][0] = y0; acc2[i][j][1] = y1;
            acc2[i][j][2] = y2; acc2[i][j][3] = y3;
            s  += y0 + y1 + y2 + y3;
            q2 += y0*y0 + y1*y1 + y2*y2 + y3*y3;
        }
        s  += __shfl_xor(s, 16, 64);  s  += __shfl_xor(s, 32, 64);
        q2 += __shfl_xor(q2, 16, 64); q2 += __shfl_xor(q2, 32, 64);
        if (lq == 0) {
            int half = wm >> 6;
            sums[half * 128 + nl] = s;
            ssqs[half * 128 + nl] = q2;
        }
    }
    __syncthreads();

    #pragma unroll
    for (int j = 0; j < 4; ++j) {
        int nl = wn + j * 16 + lr;
        int node = rb + nl;
        if (node >= N_NODES) continue;
        float tot = sums[nl] + sums[128 + nl];
        float tq  = ssqs[nl] + ssqs[128 + nl];
        float mu  = tot * (1.0f / 128.0f);
        float var = tq * (1.0f / 128.0f) - mu * mu;
        float rs  = rsqrtf(var + LN_EPS);
        #pragma unroll
        for (int i = 0; i < 4; ++i) {
            int wc = wm + i * 16 + lq * 4;
            float4 gv = *(const float4*)(g2 + wc);
            float4 ev = *(const float4*)(be2 + wc);
            float4 o;
            o.x = (acc2[i][j][0] - mu) * rs * gv.x + ev.x;
            o.y = (acc2[i][j][1] - mu) * rs * gv.y + ev.y;
            o.z = (acc2[i][j][2] - mu) * rs * gv.z + ev.z;
            o.w = (acc2[i][j][3] - mu) * rs * gv.w + ev.w;
            *(float4*)(out + (size_t)node * 128 + wc) = o;
        }
    }
}

// ---------------------------------------------------------------------------
extern "C" void kernel_launch(void* const* d_in, const int* in_sizes, int n_in,
                              void* d_out, int out_size, void* d_ws, size_t ws_size,
                              hipStream_t stream)
{
    const float* x    = (const float*)d_in[0];
    const int*   ei   = (const int*)  d_in[1];
    const float* Wl   = (const float*)d_in[2];
    const float* bl   = (const float*)d_in[3];
    const float* Wr   = (const float*)d_in[4];
    const float* br   = (const float*)d_in[5];
    const float* att  = (const float*)d_in[6];
    const float* bias = (const float*)d_in[7];
    const float* g1   = (const float*)d_in[8];
    const float* be1  = (const float*)d_in[9];
    const float* W1   = (const float*)d_in[10];
    const float* b1   = (const float*)d_in[11];
    const float* W2   = (const float*)d_in[12];
    const float* b2   = (const float*)d_in[13];
    const float* g2   = (const float*)d_in[14];
    const float* be2  = (const float*)d_in[15];
    float* out = (float*)d_out;

    char* ws = (char*)d_ws;
    size_t off = 0;
    auto alloc = [&](size_t bytes) -> void* {
        void* p = ws + off;
        off = (off + bytes + 255) & ~(size_t)255;
        return p;
    };
    ushort* xlb  = (ushort*)alloc((size_t)N_NODES * 512 * 2);
    ushort* xrb  = (ushort*)alloc((size_t)N_NODES * 512 * 2);
    ushort* x1b  = (ushort*)alloc((size_t)N_NODES * 128 * 2);
    ushort* wb   = (ushort*)alloc((size_t)197120 * 2);
    int*   offs    = (int*)alloc((size_t)(N_NODES + 1) * 4);
    int*   counts  = (int*)alloc((size_t)N_NODES * 4 * 2);  // counts + cursor
    int*   cursor  = counts + N_NODES;
    unsigned long long* state = (unsigned long long*)alloc(256 * 4);
    int*   srcList = (int*)alloc((size_t)EN_TOT * 4);

    ushort* wcat = wb;              // [Wl;Wr] 1024x128
    ushort* w1b  = wb + 131072;
    ushort* w2b  = wb + 163840;
    ushort* attb = wb + 196608;

    prep<<<770, 256, 0, stream>>>(Wl, Wr, W1, W2, att, wb, counts, (int*)state);

    gemm_lr<<<391, 256, 0, stream>>>(x, wcat, bl, br, xlb, xrb,
                                     ei + N_EDGES, counts);

    scan_lb<<<NC_SCAN, 64, 0, stream>>>(counts, offs, state);
    scatter_edges<<<(EN_TOT + 255) / 256, 256, 0, stream>>>(ei, ei + N_EDGES,
                                                           offs, cursor, srcList);

    gat_fused<<<12500, 256, 0, stream>>>(x, xlb, xrb, offs, srcList, attb,
                                         bias, g1, be1, x1b);

    ffn_fused<<<391, 256, 0, stream>>>(x1b, w1b, b1, w2b, b2, g2, be2, out);
}